// Round 17
// baseline (261.480 us; speedup 1.0000x reference)
//
#include <hip/hip_runtime.h>

#define NB 32
#define NL 512
#define ND 512
#define NH 1024
#define NE 8
#define NROWS (NB * NL)       // 16384
#define CW 2048               // C width = [U|V]
#define SPAD 136              // LDS row pad for stage buffers (16B-aligned)

typedef __attribute__((ext_vector_type(8))) short bf16x8;
typedef __attribute__((ext_vector_type(4))) float f32x4;
typedef __attribute__((ext_vector_type(4))) unsigned u32x4;

__device__ __forceinline__ unsigned short f2bf(float f) {
    unsigned u = __float_as_uint(f);
    return (unsigned short)((u + 0x7fffu + ((u >> 16) & 1u)) >> 16);
}
__device__ __forceinline__ float bf2f(unsigned short b) {
    return __uint_as_float(((unsigned)b) << 16);
}
// truncating bf16 pack of two floats: one v_perm_b32
__device__ __forceinline__ unsigned pktr(float a, float b) {
    return __builtin_amdgcn_perm(__float_as_uint(b), __float_as_uint(a), 0x07060302u);
}

// ---------- W prep: transpose + RNE split, packed [ntg][kb][lane][jp] ----------
__global__ __launch_bounds__(256) void wprep(
    const float* __restrict__ Wt, const float* __restrict__ Ws,
    unsigned* __restrict__ bpack)
{
    __shared__ float tile[64][65];
    int bid = blockIdx.x;
    int mat = bid >> 7, rem = bid & 127;
    int kt0 = (rem >> 4) << 6;
    int nt0 = (rem & 15) << 6;
    const float* W = mat ? Ws : Wt;
    unsigned* Oh = bpack;
    unsigned* Ol = bpack + 524288u;
    int t = threadIdx.x;
    #pragma unroll
    for (int i = 0; i < 16; ++i) {
        int idx = t + 256 * i;
        int k = idx >> 6, n = idx & 63;
        tile[k][n] = W[(size_t)(kt0 + k) * NH + nt0 + n];
    }
    __syncthreads();
    #pragma unroll
    for (int i = 0; i < 8; ++i) {
        int idx = t + 256 * i;
        int jp = idx & 3, lane = (idx >> 2) & 63, kbr = (idx >> 8) & 1, ntr = (idx >> 9) & 3;
        int ncol = ntr * 16 + (lane & 15);
        int kcol = kbr * 32 + ((lane >> 4) << 3) + jp * 2;
        float w0 = tile[kcol][ncol], w1 = tile[kcol + 1][ncol];
        unsigned short h0 = f2bf(w0), h1 = f2bf(w1);
        unsigned short l0 = f2bf(w0 - bf2f(h0)), l1 = f2bf(w1 - bf2f(h1));
        int ntg = mat * 64 + (nt0 >> 4) + ntr;
        int kb = (kt0 >> 5) + kbr;
        unsigned offs = ((unsigned)(ntg * 16 + kb) * 64u + (unsigned)lane) * 4u + jp;
        Oh[offs] = (unsigned)h0 | ((unsigned)h1 << 16);
        Ol[offs] = (unsigned)l0 | ((unsigned)l1 << 16);
    }
}

// ---------- gemm_all: blocks 0..255 = exact; 256..1279 = main (barrier-free k-loop) ----------
__global__ __launch_bounds__(512, 4) void gemm_all(
    const float* __restrict__ x, const unsigned* __restrict__ bpack,
    unsigned short* __restrict__ C, unsigned short* __restrict__ Clo)
{
    __shared__ unsigned short cs[64][264];   // epilogue staging only

    const int tid = threadIdx.x, lane = tid & 63, wave = tid >> 6;
    const int g = lane >> 4, c = lane & 15;

    if (blockIdx.x >= 256) {
        // ============ main path: 128x256 tile, 1-term bf16, NO barriers in k-loop ============
        const int wm = wave >> 2, wn = wave & 3;
        const int bid = blockIdx.x - 256;
        const int xcd = bid & 7, idx = bid >> 3;
        const int mi = xcd * 16 + (idx >> 3), ni = idx & 7;
        const int m0 = mi * 128;

        f32x4 acc[4][4];
        #pragma unroll
        for (int nf = 0; nf < 4; ++nf)
            #pragma unroll
            for (int mf = 0; mf < 4; ++mf) acc[nf][mf] = (f32x4){0.f, 0.f, 0.f, 0.f};

        // lane's A base: row = m0 + wm*64 + mf*16 + c, k-offset g*8 (4 lanes/row -> 128B lines)
        const float* xfrag = x + (size_t)(m0 + wm * 64 + c) * ND + g * 8;
        const unsigned* bbase = bpack + ((size_t)(ni * 16 + wn * 4) * 16) * 256 + (size_t)lane * 4;

        #pragma unroll 2
        for (int kb = 0; kb < 16; ++kb) {
            bf16x8 af[4];
            #pragma unroll
            for (int mf = 0; mf < 4; ++mf) {
                const float* pa = xfrag + (size_t)(mf * 16) * ND + kb * 32;
                float4 a0 = *(const float4*)pa;
                float4 a1 = *(const float4*)(pa + 4);
                u32x4 u;
                u.x = pktr(a0.x, a0.y); u.y = pktr(a0.z, a0.w);
                u.z = pktr(a1.x, a1.y); u.w = pktr(a1.z, a1.w);
                af[mf] = __builtin_bit_cast(bf16x8, u);
            }
            #pragma unroll
            for (int nf = 0; nf < 4; ++nf) {
                bf16x8 bfr = *(const bf16x8*)(bbase + ((size_t)(nf * 16 + kb) * 64) * 4);
                #pragma unroll
                for (int mf = 0; mf < 4; ++mf)
                    acc[nf][mf] = __builtin_amdgcn_mfma_f32_16x16x32_bf16(af[mf], bfr, acc[nf][mf], 0, 0, 0);
            }
        }

        #pragma unroll
        for (int ph = 0; ph < 2; ++ph) {
            __syncthreads();
            if (wm == ph) {
                #pragma unroll
                for (int nf = 0; nf < 4; ++nf)
                    #pragma unroll
                    for (int mf = 0; mf < 4; ++mf)
                        #pragma unroll
                        for (int r = 0; r < 4; ++r)
                            cs[mf * 16 + g * 4 + r][wn * 64 + nf * 16 + c] =
                                (unsigned short)(__float_as_uint(acc[nf][mf][r]) >> 16);
            }
            __syncthreads();
            int row = tid >> 3, ch = tid & 7;
            int grow = m0 + ph * 64 + row;
            if ((grow & 511) >= 32) {                // exact blocks own rows l<32
                unsigned short* dst = &C[(size_t)grow * CW + ni * 256 + ch * 32];
                #pragma unroll
                for (int q = 0; q < 4; ++q)
                    *(uint4*)(dst + q * 8) = *(const uint4*)&cs[row][ch * 32 + q * 8];
            }
        }
    } else {
        // ============ exact path: 3-term fp32-split, rows 0..31/batch, 8 waves ============
        const int eb = blockIdx.x;
        const int bq = eb >> 3, ni = eb & 7;
        const int m0 = bq * NL;
        const unsigned* Bhi = bpack;
        const unsigned* Blo = bpack + 524288u;

        f32x4 acc[2][2];
        #pragma unroll
        for (int nf = 0; nf < 2; ++nf)
            #pragma unroll
            for (int mf = 0; mf < 2; ++mf) acc[nf][mf] = (f32x4){0.f, 0.f, 0.f, 0.f};

        const float* xr0 = x + (size_t)(m0 + c) * ND + g * 8;
        #pragma unroll 2
        for (int kb = 0; kb < 16; ++kb) {
            bf16x8 ah[2], al[2];
            #pragma unroll
            for (int mf = 0; mf < 2; ++mf) {
                const float* p = xr0 + mf * (16 * ND) + kb * 32;
                float4 a0 = *(const float4*)p;
                float4 a1 = *(const float4*)(p + 4);
                float f[8] = {a0.x, a0.y, a0.z, a0.w, a1.x, a1.y, a1.z, a1.w};
                float lo[8];
                #pragma unroll
                for (int j = 0; j < 8; ++j) {
                    float hif = __uint_as_float(__float_as_uint(f[j]) & 0xFFFF0000u);
                    lo[j] = f[j] - hif;
                }
                u32x4 uh, ul;
                uh.x = pktr(f[0], f[1]); uh.y = pktr(f[2], f[3]);
                uh.z = pktr(f[4], f[5]); uh.w = pktr(f[6], f[7]);
                ul.x = pktr(lo[0], lo[1]); ul.y = pktr(lo[2], lo[3]);
                ul.z = pktr(lo[4], lo[5]); ul.w = pktr(lo[6], lo[7]);
                ah[mf] = __builtin_bit_cast(bf16x8, uh);
                al[mf] = __builtin_bit_cast(bf16x8, ul);
            }
            #pragma unroll
            for (int nf = 0; nf < 2; ++nf) {
                int nt = ni * 16 + wave * 2 + nf;
                size_t bo = ((size_t)(nt * 16 + kb) * 64 + lane) * 4;
                bf16x8 bh = *(const bf16x8*)(Bhi + bo);
                bf16x8 bl = *(const bf16x8*)(Blo + bo);
                #pragma unroll
                for (int mf = 0; mf < 2; ++mf) {
                    acc[nf][mf] = __builtin_amdgcn_mfma_f32_16x16x32_bf16(ah[mf], bh, acc[nf][mf], 0, 0, 0);
                    acc[nf][mf] = __builtin_amdgcn_mfma_f32_16x16x32_bf16(al[mf], bh, acc[nf][mf], 0, 0, 0);
                    acc[nf][mf] = __builtin_amdgcn_mfma_f32_16x16x32_bf16(ah[mf], bl, acc[nf][mf], 0, 0, 0);
                }
            }
        }

        // hi out: rows 0..31 x 256 cols, all 8 waves
        #pragma unroll
        for (int nf = 0; nf < 2; ++nf)
            #pragma unroll
            for (int mf = 0; mf < 2; ++mf)
                #pragma unroll
                for (int r = 0; r < 4; ++r)
                    cs[mf * 16 + g * 4 + r][(wave * 2 + nf) * 16 + c] =
                        (unsigned short)(__float_as_uint(acc[nf][mf][r]) >> 16);
        __syncthreads();
        #pragma unroll
        for (int i = 0; i < 2; ++i) {
            int id = tid + 512 * i;
            int row = id >> 5, cg = id & 31;
            *(uint4*)&C[(size_t)(m0 + row) * CW + ni * 256 + cg * 8] = *(const uint4*)&cs[row][cg * 8];
        }
        __syncthreads();
        // lo out (rows 0..19)
        #pragma unroll
        for (int nf = 0; nf < 2; ++nf)
            #pragma unroll
            for (int mf = 0; mf < 2; ++mf)
                #pragma unroll
                for (int r = 0; r < 4; ++r) {
                    float v = acc[nf][mf][r];
                    float hif = __uint_as_float(__float_as_uint(v) & 0xFFFF0000u);
                    cs[mf * 16 + g * 4 + r][(wave * 2 + nf) * 16 + c] =
                        (unsigned short)(__float_as_uint(v - hif) >> 16);
                }
        __syncthreads();
        #pragma unroll
        for (int i = 0; i < 2; ++i) {
            int id = tid + 512 * i;
            int row = id >> 5, cg = id & 31;
            if (row < 20)
                *(uint4*)&Clo[((size_t)bq * 20 + row) * CW + ni * 256 + cg * 8] = *(const uint4*)&cs[row][cg * 8];
        }
    }
}

// ---------- stats_all: blocks 0..1023 = bf16 stats; 1024..1087 = exact stats ----------
__global__ __launch_bounds__(256) void stats_all(
    const unsigned short* __restrict__ C, const unsigned short* __restrict__ Clo,
    const float* __restrict__ bt, const float* __restrict__ bs,
    float* __restrict__ rowpart, float* __restrict__ exstat)
{
    __shared__ unsigned short stg[88][SPAD];
    const int tid = threadIdx.x;

    if (blockIdx.x < 1024) {
        const int bid = blockIdx.x;
        const int q = bid & 3, lc = (bid >> 2) & 7, b = bid >> 5;
        const int l0 = lc * 64;
        const int cq = tid & 31, rg = tid >> 5;
        const float inv25 = 1.f / 25.f;

        float s[8], qa[8];
        #pragma unroll
        for (int r = 0; r < 8; ++r) { s[r] = 0.f; qa[r] = 0.f; }

        for (int ch = 0; ch < 4; ++ch) {
            int cb = q * 512 + ch * 128;
            __syncthreads();
            for (int i = tid; i < 1408; i += 256) {
                int si = i >> 4, cg = i & 15;
                int gl = l0 - 12 + si;
                gl = gl < 0 ? 0 : (gl > NL - 1 ? NL - 1 : gl);
                *(uint4*)&stg[si][cg * 8] = *(const uint4*)&C[(size_t)(b * NL + gl) * CW + cb + cg * 8];
            }
            __syncthreads();

            float bv[4];
            {
                float4 b4 = q < 2 ? *(const float4*)&bt[cb + cq * 4]
                                  : *(const float4*)&bs[cb - 1024 + cq * 4];
                bv[0] = b4.x; bv[1] = b4.y; bv[2] = b4.z; bv[3] = b4.w;
            }
            float run[4] = {0.f, 0.f, 0.f, 0.f};
            #pragma unroll
            for (int w = 0; w < 25; ++w) {
                ushort4 u = *(const ushort4*)&stg[rg * 8 + w][cq * 4];
                run[0] += bf2f(u.x); run[1] += bf2f(u.y); run[2] += bf2f(u.z); run[3] += bf2f(u.w);
            }
            #pragma unroll
            for (int rr = 0; rr < 8; ++rr) {
                if (rr > 0) {
                    ushort4 un = *(const ushort4*)&stg[rg * 8 + rr + 24][cq * 4];
                    ushort4 uo = *(const ushort4*)&stg[rg * 8 + rr - 1][cq * 4];
                    run[0] += bf2f(un.x) - bf2f(uo.x); run[1] += bf2f(un.y) - bf2f(uo.y);
                    run[2] += bf2f(un.z) - bf2f(uo.z); run[3] += bf2f(un.w) - bf2f(uo.w);
                }
                float pre[4];
                if (q < 2) {
                    ushort4 uc = *(const ushort4*)&stg[rg * 8 + rr + 12][cq * 4];
                    pre[0] = bf2f(uc.x) - run[0] * inv25 + bv[0];
                    pre[1] = bf2f(uc.y) - run[1] * inv25 + bv[1];
                    pre[2] = bf2f(uc.z) - run[2] * inv25 + bv[2];
                    pre[3] = bf2f(uc.w) - run[3] * inv25 + bv[3];
                } else {
                    pre[0] = run[0] * inv25 + bv[0];
                    pre[1] = run[1] * inv25 + bv[1];
                    pre[2] = run[2] * inv25 + bv[2];
                    pre[3] = run[3] * inv25 + bv[3];
                }
                s[rr]  += pre[0] + pre[1] + pre[2] + pre[3];
                qa[rr] += pre[0] * pre[0] + pre[1] * pre[1] + pre[2] * pre[2] + pre[3] * pre[3];
            }
        }

        #pragma unroll
        for (int rr = 0; rr < 8; ++rr)
            #pragma unroll
            for (int o = 1; o < 32; o <<= 1) {
                s[rr]  += __shfl_xor(s[rr], o);
                qa[rr] += __shfl_xor(qa[rr], o);
            }
        if (cq == 0) {
            #pragma unroll
            for (int rr = 0; rr < 8; ++rr) {
                size_t gr = (size_t)b * NL + l0 + rg * 8 + rr;
                rowpart[(gr * 4 + q) * 2 + 0] = s[rr];
                rowpart[(gr * 4 + q) * 2 + 1] = qa[rr];
            }
        }
    } else {
        // exact stats: one wave per (b, chunk) instance
        const int inst = (blockIdx.x - 1024) * 4 + (tid >> 6);
        const int b = inst >> 3, chunk = inst & 7;
        const int t = tid & 63;
        const int c4 = chunk * 256 + t * 4;
        const bool isU = chunk < 4;
        const float inv25 = 1.f / 25.f;

        float bias[4];
        {
            float4 b4 = isU ? *(const float4*)&bt[c4] : *(const float4*)&bs[c4 - 1024];
            bias[0] = b4.x; bias[1] = b4.y; bias[2] = b4.z; bias[3] = b4.w;
        }
        float s[8], q[8];
        #pragma unroll
        for (int r = 0; r < 8; ++r) { s[r] = 0.f; q[r] = 0.f; }

        float cs2[4] = {0, 0, 0, 0}, v0[4], keep[8][4];
        #pragma unroll
        for (int j = 0; j < 20; ++j) {
            ushort4 h  = *(const ushort4*)&C[(size_t)(b * NL + j) * CW + c4];
            ushort4 lo = *(const ushort4*)&Clo[((size_t)b * 20 + j) * CW + c4];
            float u[4] = {bf2f(h.x) + bf2f(lo.x), bf2f(h.y) + bf2f(lo.y),
                          bf2f(h.z) + bf2f(lo.z), bf2f(h.w) + bf2f(lo.w)};
            if (j == 0) {
                #pragma unroll
                for (int k = 0; k < 4; ++k) v0[k] = u[k];
            }
            if (j < 8) {
                #pragma unroll
                for (int k = 0; k < 4; ++k) keep[j][k] = u[k];
            }
            #pragma unroll
            for (int k = 0; k < 4; ++k) cs2[k] += u[k];
            if (j >= 12) {
                const int l = j - 12;
                const float w0 = (float)(24 - j);
                #pragma unroll
                for (int k = 0; k < 4; ++k) {
                    float ma = (cs2[k] + w0 * v0[k]) * inv25;
                    float pre = isU ? (keep[l][k] - ma + bias[k]) : (ma + bias[k]);
                    s[l] += pre;
                    q[l] += pre * pre;
                }
            }
        }
        #pragma unroll
        for (int r = 0; r < 8; ++r)
            #pragma unroll
            for (int o = 1; o < 64; o <<= 1) {
                s[r] += __shfl_xor(s[r], o);
                q[r] += __shfl_xor(q[r], o);
            }
        if (t == 0) {
            #pragma unroll
            for (int r = 0; r < 8; ++r) {
                exstat[(((size_t)b * 8 + chunk) * 8 + r) * 2 + 0] = s[r];
                exstat[(((size_t)b * 8 + chunk) * 8 + r) * 2 + 1] = q[r];
            }
        }
    }
}

// ---------- exact_apply: exact med + W2 logit partials, per 128-h-col slice ----------
__global__ __launch_bounds__(64) void exact_apply(
    const unsigned short* __restrict__ C, const unsigned short* __restrict__ Clo,
    const float* __restrict__ bt, const float* __restrict__ gt, const float* __restrict__ bet,
    const float* __restrict__ bs, const float* __restrict__ gs, const float* __restrict__ bes,
    const float* __restrict__ W2, const float* __restrict__ exstat,
    float* __restrict__ exlg)
{
    const int t = threadIdx.x;
    const int chunk = blockIdx.x & 7, b = blockIdx.x >> 3;
    const int h2 = chunk * 128 + t * 2;
    const float inv25 = 1.f / 25.f;

    float mu_t[8], rs_t[8], mu_s[8], rs_s[8];
    #pragma unroll
    for (int l = 0; l < 8; ++l) {
        float st = 0.f, qt = 0.f, ss = 0.f, qs = 0.f;
        #pragma unroll
        for (int ch = 0; ch < 4; ++ch) {
            st += exstat[(((size_t)b * 8 + ch) * 8 + l) * 2 + 0];
            qt += exstat[(((size_t)b * 8 + ch) * 8 + l) * 2 + 1];
            ss += exstat[(((size_t)b * 8 + 4 + ch) * 8 + l) * 2 + 0];
            qs += exstat[(((size_t)b * 8 + 4 + ch) * 8 + l) * 2 + 1];
        }
        mu_t[l] = st * (1.f / NH);
        rs_t[l] = rsqrtf(qt * (1.f / NH) - mu_t[l] * mu_t[l] + 1e-5f);
        mu_s[l] = ss * (1.f / NH);
        rs_s[l] = rsqrtf(qs * (1.f / NH) - mu_s[l] * mu_s[l] + 1e-5f);
    }

    float btv[2], gtv[2], bev[2], bsv[2], gsv[2], besv[2], w2r[2][NE];
    #pragma unroll
    for (int k = 0; k < 2; ++k) {
        int h = h2 + k;
        btv[k] = bt[h]; gtv[k] = gt[h]; bev[k] = bet[h];
        bsv[k] = bs[h]; gsv[k] = gs[h]; besv[k] = bes[h];
        const float4* wp = (const float4*)&W2[(size_t)h * NE];
        float4 a = wp[0], c2 = wp[1];
        w2r[k][0] = a.x;  w2r[k][1] = a.y;  w2r[k][2] = a.z;  w2r[k][3] = a.w;
        w2r[k][4] = c2.x; w2r[k][5] = c2.y; w2r[k][6] = c2.z; w2r[k][7] = c2.w;
    }

    float csU[2] = {0, 0}, csV[2] = {0, 0}, v0U[2], v0V[2], keepU[8][2];
    float lg[8][NE];
    #pragma unroll
    for (int l = 0; l < 8; ++l)
        #pragma unroll
        for (int e = 0; e < NE; ++e) lg[l][e] = 0.f;

    #pragma unroll
    for (int j = 0; j < 20; ++j) {
        size_t rb = (size_t)(b * NL + j) * CW;
        size_t lb = ((size_t)b * 20 + j) * CW;
        ushort2 hu  = *(const ushort2*)&C[rb + h2];
        ushort2 lu  = *(const ushort2*)&Clo[lb + h2];
        ushort2 hv  = *(const ushort2*)&C[rb + NH + h2];
        ushort2 lv  = *(const ushort2*)&Clo[lb + NH + h2];
        float u[2] = {bf2f(hu.x) + bf2f(lu.x), bf2f(hu.y) + bf2f(lu.y)};
        float v[2] = {bf2f(hv.x) + bf2f(lv.x), bf2f(hv.y) + bf2f(lv.y)};
        if (j == 0) {
            #pragma unroll
            for (int k = 0; k < 2; ++k) { v0U[k] = u[k]; v0V[k] = v[k]; }
        }
        if (j < 8) {
            #pragma unroll
            for (int k = 0; k < 2; ++k) keepU[j][k] = u[k];
        }
        #pragma unroll
        for (int k = 0; k < 2; ++k) { csU[k] += u[k]; csV[k] += v[k]; }
        if (j >= 12) {
            const int l = j - 12;
            const float w0 = (float)(24 - j);
            #pragma unroll
            for (int k = 0; k < 2; ++k) {
                float maU = (csU[k] + w0 * v0U[k]) * inv25;
                float maV = (csV[k] + w0 * v0V[k]) * inv25;
                float tn = ((keepU[l][k] - maU + btv[k]) - mu_t[l]) * rs_t[l] * gtv[k] + bev[k];
                float sn = ((maV + bsv[k]) - mu_s[l]) * rs_s[l] * gsv[k] + besv[k];
                float m = tn + sn; m = m > 0.f ? m : 0.f;
                #pragma unroll
                for (int e = 0; e < NE; ++e) lg[l][e] = fmaf(m, w2r[k][e], lg[l][e]);
            }
        }
    }
    #pragma unroll
    for (int l = 0; l < 8; ++l)
        #pragma unroll
        for (int e = 0; e < NE; ++e)
            #pragma unroll
            for (int o = 1; o < 64; o <<= 1)
                lg[l][e] += __shfl_xor(lg[l][e], o);
    if (t == 0) {
        #pragma unroll
        for (int l = 0; l < 8; ++l)
            #pragma unroll
            for (int e = 0; e < NE; ++e)
                exlg[(((size_t)b * 8 + chunk) * 8 + l) * NE + e] = lg[l][e];
    }
}

// ---------- apply_k: MA+LN+med+W2 logit partials per col-quarter ----------
__global__ __launch_bounds__(256) void apply_k(
    const unsigned short* __restrict__ C,
    const float* __restrict__ bt, const float* __restrict__ gt, const float* __restrict__ bet,
    const float* __restrict__ bs, const float* __restrict__ gs, const float* __restrict__ bes,
    const float* __restrict__ W2, const float* __restrict__ rowpart,
    float* __restrict__ lgpart)
{
    __shared__ unsigned short stgU[88][SPAD];
    __shared__ unsigned short stgV[88][SPAD];
    __shared__ float4 rowstat[64];

    const int tid = threadIdx.x;
    const int bid = blockIdx.x;
    const int q = bid & 3, lc = (bid >> 2) & 7, b = bid >> 5;
    const int l0 = lc * 64;
    const int cq = tid & 31, rg = tid >> 5;
    const float inv25 = 1.f / 25.f;

    if (tid < 64) {
        size_t gr = (size_t)b * NL + l0 + tid;
        const float* p = &rowpart[gr * 8];
        float st = p[0] + p[2], qt = p[1] + p[3];
        float ss = p[4] + p[6], qs = p[5] + p[7];
        float mut = st * (1.f / NH), mus = ss * (1.f / NH);
        float vt = qt * (1.f / NH) - mut * mut;
        float vs = qs * (1.f / NH) - mus * mus;
        rowstat[tid] = make_float4(mut, rsqrtf(vt + 1e-5f), mus, rsqrtf(vs + 1e-5f));
    }

    float lgp[8][NE];
    #pragma unroll
    for (int r = 0; r < 8; ++r)
        #pragma unroll
        for (int e = 0; e < NE; ++e) lgp[r][e] = 0.f;

    for (int ch = 0; ch < 2; ++ch) {
        int hb = q * 256 + ch * 128;
        __syncthreads();
        for (int i = tid; i < 1408; i += 256) {
            int si = i >> 4, cg = i & 15;
            int gl = l0 - 12 + si;
            gl = gl < 0 ? 0 : (gl > NL - 1 ? NL - 1 : gl);
            size_t rb = (size_t)(b * NL + gl) * CW;
            *(uint4*)&stgU[si][cg * 8] = *(const uint4*)&C[rb + hb + cg * 8];
            *(uint4*)&stgV[si][cg * 8] = *(const uint4*)&C[rb + NH + hb + cg * 8];
        }
        __syncthreads();

        int col = hb + cq * 4;
        float4 btv = *(const float4*)&bt[col],  gtv = *(const float4*)&gt[col];
        float4 bev = *(const float4*)&bet[col], bsv = *(const float4*)&bs[col];
        float4 gsv = *(const float4*)&gs[col],  besv = *(const float4*)&bes[col];
        float btr[4] = {btv.x, btv.y, btv.z, btv.w};
        float gtr[4] = {gtv.x, gtv.y, gtv.z, gtv.w};
        float ber[4] = {bev.x, bev.y, bev.z, bev.w};
        float bsr[4] = {bsv.x, bsv.y, bsv.z, bsv.w};
        float gsr[4] = {gsv.x, gsv.y, gsv.z, gsv.w};
        float besr[4] = {besv.x, besv.y, besv.z, besv.w};
        float w2r[4][NE];
        #pragma unroll
        for (int j = 0; j < 4; ++j) {
            const float4* wp = (const float4*)&W2[(size_t)(col + j) * NE];
            float4 a = wp[0], c2 = wp[1];
            w2r[j][0] = a.x;  w2r[j][1] = a.y;  w2r[j][2] = a.z;  w2r[j][3] = a.w;
            w2r[j][4] = c2.x; w2r[j][5] = c2.y; w2r[j][6] = c2.z; w2r[j][7] = c2.w;
        }

        float runU[4] = {0.f, 0.f, 0.f, 0.f}, runV[4] = {0.f, 0.f, 0.f, 0.f};
        #pragma unroll
        for (int w = 0; w < 25; ++w) {
            ushort4 u = *(const ushort4*)&stgU[rg * 8 + w][cq * 4];
            ushort4 v = *(const ushort4*)&stgV[rg * 8 + w][cq * 4];
            runU[0] += bf2f(u.x); runU[1] += bf2f(u.y); runU[2] += bf2f(u.z); runU[3] += bf2f(u.w);
            runV[0] += bf2f(v.x); runV[1] += bf2f(v.y); runV[2] += bf2f(v.z); runV[3] += bf2f(v.w);
        }
        #pragma unroll
        for (int rr = 0; rr < 8; ++rr) {
            if (rr > 0) {
                ushort4 un = *(const ushort4*)&stgU[rg * 8 + rr + 24][cq * 4];
                ushort4 uo = *(const ushort4*)&stgU[rg * 8 + rr - 1][cq * 4];
                ushort4 vn = *(const ushort4*)&stgV[rg * 8 + rr + 24][cq * 4];
                ushort4 vo = *(const ushort4*)&stgV[rg * 8 + rr - 1][cq * 4];
                runU[0] += bf2f(un.x) - bf2f(uo.x); runU[1] += bf2f(un.y) - bf2f(uo.y);
                runU[2] += bf2f(un.z) - bf2f(uo.z); runU[3] += bf2f(un.w) - bf2f(uo.w);
                runV[0] += bf2f(vn.x) - bf2f(vo.x); runV[1] += bf2f(vn.y) - bf2f(vo.y);
                runV[2] += bf2f(vn.z) - bf2f(vo.z); runV[3] += bf2f(vn.w) - bf2f(vo.w);
            }
            float4 rs = rowstat[rg * 8 + rr];
            ushort4 uc = *(const ushort4*)&stgU[rg * 8 + rr + 12][cq * 4];
            float cen[4] = {bf2f(uc.x), bf2f(uc.y), bf2f(uc.z), bf2f(uc.w)};
            float med[4];
            #pragma unroll
            for (int j = 0; j < 4; ++j) {
                float tn = ((cen[j] - runU[j] * inv25 + btr[j]) - rs.x) * rs.y * gtr[j] + ber[j];
                float sn = ((runV[j] * inv25 + bsr[j]) - rs.z) * rs.w * gsr[j] + besr[j];
                float m = tn + sn;
                med[j] = m > 0.f ? m : 0.f;
            }
            #pragma unroll
            for (int e = 0; e < NE; ++e)
                lgp[rr][e] = fmaf(med[0], w2r[0][e], fmaf(med[1], w2r[1][e],
                             fmaf(med[2], w2r[2][e], fmaf(med[3], w2r[3][e], lgp[rr][e]))));
        }
    }

    #pragma unroll
    for (int rr = 0; rr < 8; ++rr)
        #pragma unroll
        for (int e = 0; e < NE; ++e)
            #pragma unroll
            for (int o = 1; o < 32; o <<= 1)
                lgp[rr][e] += __shfl_xor(lgp[rr][e], o);
    if (cq == 0) {
        #pragma unroll
        for (int rr = 0; rr < 8; ++rr) {
            size_t gr = (size_t)b * NL + l0 + rg * 8 + rr;
            #pragma unroll
            for (int e = 0; e < NE; ++e)
                lgpart[(gr * 4 + q) * NE + e] = lgp[rr][e];
        }
    }
}

// ---------- final_all: blocks 0..63 = mask top2; block 64 = exact gates ----------
__global__ __launch_bounds__(256) void final_all(
    const float* __restrict__ lgpart, const float* __restrict__ exlg,
    const float* __restrict__ b2,
    unsigned* __restrict__ mb, float* __restrict__ gates)
{
    const int t = threadIdx.x;
    if (blockIdx.x < 64) {
        int row = blockIdx.x * 256 + t;
        int b = row >> 9, l = row & (NL - 1);
        float lg[NE];
        #pragma unroll
        for (int e = 0; e < NE; ++e) lg[e] = b2[e];
        #pragma unroll
        for (int qq = 0; qq < 4; ++qq)
            #pragma unroll
            for (int e = 0; e < NE; ++e)
                lg[e] += lgpart[((size_t)row * 4 + qq) * NE + e];
        int i0 = 0;
        #pragma unroll
        for (int e = 1; e < NE; ++e) if (lg[e] > lg[i0]) i0 = e;
        int i1 = i0 == 0 ? 1 : 0;
        #pragma unroll
        for (int e = 0; e < NE; ++e) if (e != i0 && lg[e] > lg[i1]) i1 = e;
        unsigned m = (l < 8) ? 0u : ((1u << i0) | (1u << (8 + i1)));
        #pragma unroll
        for (int o = 1; o < 64; o <<= 1) m |= __shfl_xor(m, o);
        if ((t & 63) == 0) {
            atomicOr(&mb[2 * b + 0], m & 0xffu);
            atomicOr(&mb[2 * b + 1], m >> 8);
        }
    } else {
        const int b = t >> 3, l = t & 7;
        float lg[NE];
        #pragma unroll
        for (int e = 0; e < NE; ++e) lg[e] = b2[e];
        #pragma unroll
        for (int ch = 0; ch < 8; ++ch)
            #pragma unroll
            for (int e = 0; e < NE; ++e)
                lg[e] += exlg[(((size_t)b * 8 + ch) * 8 + l) * NE + e];
        float mx = lg[0];
        #pragma unroll
        for (int e = 1; e < NE; ++e) mx = lg[e] > mx ? lg[e] : mx;
        float p[NE]; float sum = 0.f;
        #pragma unroll
        for (int e = 0; e < NE; ++e) { p[e] = expf(lg[e] - mx); sum += p[e]; }
        float inv = 1.f / sum;
        #pragma unroll
        for (int e = 0; e < NE; ++e)
            gates[((size_t)b * 8 + l) * NE + e] = p[e] * inv;
        int i0 = 0;
        #pragma unroll
        for (int e = 1; e < NE; ++e) if (lg[e] > lg[i0]) i0 = e;
        int i1 = i0 == 0 ? 1 : 0;
        #pragma unroll
        for (int e = 0; e < NE; ++e) if (e != i0 && lg[e] > lg[i1]) i1 = e;
        unsigned m = (1u << i0) | (1u << (8 + i1));
        m |= __shfl_xor(m, 1); m |= __shfl_xor(m, 2); m |= __shfl_xor(m, 4);
        if (l == 0) {
            atomicOr(&mb[2 * b + 0], m & 0xffu);
            atomicOr(&mb[2 * b + 1], m >> 8);
        }
    }
}

// masked = gates * maskbit; denom = sum_b + 1e-4; out = masked/denom*64
__global__ void finalize_k(const unsigned* __restrict__ mb,
                           const float* __restrict__ gates,
                           float* __restrict__ out)
{
    int t = threadIdx.x;
    if (t >= 16) return;
    int l = t >> 1, e = t & 1;
    float m[NB];
    float sum = 0.f;
    #pragma unroll
    for (int bb = 0; bb < NB; ++bb) {
        float gvv = gates[((size_t)bb * 8 + l) * NE + e];
        float on  = ((mb[2 * bb + e] >> l) & 1u) ? 1.f : 0.f;
        m[bb] = gvv * on;
        sum += m[bb];
    }
    float scale = 64.f / (sum + 1e-4f);
    #pragma unroll
    for (int bb = 0; bb < NB; ++bb)
        out[(size_t)bb * (NL * NE) + l * NE + e] = m[bb] * scale;
}

extern "C" void kernel_launch(void* const* d_in, const int* in_sizes, int n_in,
                              void* d_out, int out_size, void* d_ws, size_t ws_size,
                              hipStream_t stream) {
    const float* x   = (const float*)d_in[0];
    const float* Wt  = (const float*)d_in[1];
    const float* bt  = (const float*)d_in[2];
    const float* gt  = (const float*)d_in[3];
    const float* bet = (const float*)d_in[4];
    const float* Ws  = (const float*)d_in[5];
    const float* bs  = (const float*)d_in[6];
    const float* gs  = (const float*)d_in[7];
    const float* bes = (const float*)d_in[8];
    const float* W2  = (const float*)d_in[9];
    const float* b2  = (const float*)d_in[10];
    float* out = (float*)d_out;

    char* wsb = (char*)d_ws;
    unsigned*       mbp     = (unsigned*)wsb;                          // 256 B
    float*          gates   = (float*)(wsb + 256);                     // 2 KB
    unsigned*       bpack   = (unsigned*)(wsb + 4096);                 // 4 MiB (dead after gemm_all)
    float*          rowpart = (float*)(wsb + 4096);                    // 512 KB (aliases bpack)
    float*          lgpart  = (float*)(wsb + 4096 + 524288);           // 2 MB   (aliases bpack)
    float*          exstat  = (float*)(wsb + 4096 + 524288 + 2097152); // 16 KB  (aliases bpack)
    float*          exlg    = (float*)(wsb + 4096 + 524288 + 2097152 + 16384); // 64 KB
    unsigned short* C       = (unsigned short*)(wsb + 4096 + 4194304); // 64 MiB
    unsigned short* Clo     = (unsigned short*)(wsb + 4096 + 4194304 + (size_t)NROWS * CW * 2);  // 2.5 MiB

    hipMemsetAsync(d_out, 0, sizeof(float) * NB * NL * NE, stream);
    hipMemsetAsync(mbp, 0, 256, stream);

    wprep<<<256, 256, 0, stream>>>(Wt, Ws, bpack);
    gemm_all<<<1280, 512, 0, stream>>>(x, bpack, C, Clo);
    stats_all<<<1088, 256, 0, stream>>>(C, Clo, bt, bs, rowpart, exstat);
    exact_apply<<<256, 64, 0, stream>>>(C, Clo, bt, gt, bet, bs, gs, bes, W2, exstat, exlg);
    apply_k<<<1024, 256, 0, stream>>>(C, bt, gt, bet, bs, gs, bes, W2, rowpart, lgpart);
    final_all<<<65, 256, 0, stream>>>(lgpart, exlg, b2, mbp, gates);
    finalize_k<<<1, 64, 0, stream>>>(mbp, gates, out);
}

// Round 18
// 183.682 us; speedup vs baseline: 1.4235x; 1.4235x over previous
//
#include <hip/hip_runtime.h>

#define NB 32
#define NL 512
#define ND 512
#define NH 1024
#define NE 8
#define NROWS (NB * NL)       // 16384
#define CW 2048               // C width = [U|V]
#define SPAD 136              // LDS row pad for stage buffers (16B-aligned)

typedef __attribute__((ext_vector_type(8))) short bf16x8;
typedef __attribute__((ext_vector_type(4))) float f32x4;
typedef __attribute__((ext_vector_type(4))) unsigned u32x4;

__device__ __forceinline__ unsigned short f2bf(float f) {
    unsigned u = __float_as_uint(f);
    return (unsigned short)((u + 0x7fffu + ((u >> 16) & 1u)) >> 16);
}
__device__ __forceinline__ float bf2f(unsigned short b) {
    return __uint_as_float(((unsigned)b) << 16);
}
// truncating bf16 pack of two floats: one v_perm_b32
__device__ __forceinline__ unsigned pktr(float a, float b) {
    return __builtin_amdgcn_perm(__float_as_uint(b), __float_as_uint(a), 0x07060302u);
}

// ---------- W prep: transpose + RNE split, packed [ntg][kb][lane][jp] ----------
__global__ __launch_bounds__(256) void wprep(
    const float* __restrict__ Wt, const float* __restrict__ Ws,
    unsigned* __restrict__ bpack)
{
    __shared__ float tile[64][65];
    int bid = blockIdx.x;
    int mat = bid >> 7, rem = bid & 127;
    int kt0 = (rem >> 4) << 6;
    int nt0 = (rem & 15) << 6;
    const float* W = mat ? Ws : Wt;
    unsigned* Oh = bpack;
    unsigned* Ol = bpack + 524288u;
    int t = threadIdx.x;
    #pragma unroll
    for (int i = 0; i < 16; ++i) {
        int idx = t + 256 * i;
        int k = idx >> 6, n = idx & 63;
        tile[k][n] = W[(size_t)(kt0 + k) * NH + nt0 + n];
    }
    __syncthreads();
    #pragma unroll
    for (int i = 0; i < 8; ++i) {
        int idx = t + 256 * i;
        int jp = idx & 3, lane = (idx >> 2) & 63, kbr = (idx >> 8) & 1, ntr = (idx >> 9) & 3;
        int ncol = ntr * 16 + (lane & 15);
        int kcol = kbr * 32 + ((lane >> 4) << 3) + jp * 2;
        float w0 = tile[kcol][ncol], w1 = tile[kcol + 1][ncol];
        unsigned short h0 = f2bf(w0), h1 = f2bf(w1);
        unsigned short l0 = f2bf(w0 - bf2f(h0)), l1 = f2bf(w1 - bf2f(h1));
        int ntg = mat * 64 + (nt0 >> 4) + ntr;
        int kb = (kt0 >> 5) + kbr;
        unsigned offs = ((unsigned)(ntg * 16 + kb) * 64u + (unsigned)lane) * 4u + jp;
        Oh[offs] = (unsigned)h0 | ((unsigned)h1 << 16);
        Ol[offs] = (unsigned)l0 | ((unsigned)l1 << 16);
    }
}

// ---------- gemm_all: blocks 0..255 = exact; 256..1279 = main (BK=128 slabs) ----------
__global__ __launch_bounds__(512, 4) void gemm_all(
    const float* __restrict__ x, const unsigned* __restrict__ bpack,
    unsigned short* __restrict__ C, unsigned short* __restrict__ Clo)
{
    __shared__ union {
        unsigned short A[2][128][128];   // 64 KB dbuf: BK=128 slab, chunk-swizzled
        unsigned short cs[64][264];
    } sm;

    const int tid = threadIdx.x, lane = tid & 63, wave = tid >> 6;
    const int g = lane >> 4, c = lane & 15;

    if (blockIdx.x >= 256) {
        // ============ main path: 128x256 tile, BK=128, 1 barrier per slab ============
        const int wm = wave >> 2, wn = wave & 3;
        const int bid = blockIdx.x - 256;
        const int xcd = bid & 7, idx = bid >> 3;
        const int mi = xcd * 16 + (idx >> 3), ni = idx & 7;
        const int m0 = mi * 128;

        f32x4 acc[4][4];
        #pragma unroll
        for (int nf = 0; nf < 4; ++nf)
            #pragma unroll
            for (int mf = 0; mf < 4; ++mf) acc[nf][mf] = (f32x4){0.f, 0.f, 0.f, 0.f};

        // staging: 2 row-halves; thread handles row h*64+(tid>>3), chunks jj and jj+8
        const int srow = tid >> 3, jj = tid & 7;

        auto loadB = [&](int kb2, int nf) -> bf16x8 {
            int nt = ni * 16 + wn * 4 + nf;
            return *(const bf16x8*)(bpack + ((size_t)(nt * 16 + kb2) * 64 + lane) * 4);
        };

        int p = 0;
        for (int s = 0; s < 4; ++s) {
            const int k0 = s * 128;
            // ---- stage slab s into buf p (4 x b128 stores/thread) ----
            #pragma unroll
            for (int h = 0; h < 2; ++h) {
                int r = h * 64 + srow;
                const float* src = x + (size_t)(m0 + r) * ND + k0;
                #pragma unroll
                for (int jq = 0; jq < 2; ++jq) {
                    int j = jj + jq * 8;             // 16B chunk index 0..15
                    float4 a0 = *(const float4*)(src + j * 8);
                    float4 a1 = *(const float4*)(src + j * 8 + 4);
                    u32x4 u;
                    u.x = pktr(a0.x, a0.y); u.y = pktr(a0.z, a0.w);
                    u.z = pktr(a1.x, a1.y); u.w = pktr(a1.z, a1.w);
                    int wc = (j ^ (r & 15)) * 8;     // chunk involution
                    *(u32x4*)&sm.A[p][r][wc] = u;
                }
            }
            __syncthreads();                         // one drain per 64 MFMAs

            #pragma unroll
            for (int kbl = 0; kbl < 4; ++kbl) {
                const int kb = s * 4 + kbl;
                bf16x8 af[4];
                #pragma unroll
                for (int mf = 0; mf < 4; ++mf) {
                    int R = wm * 64 + mf * 16 + c;
                    int chunk = kbl * 4 + g;
                    int rc = (chunk ^ (R & 15)) * 8;
                    af[mf] = *(const bf16x8*)&sm.A[p][R][rc];
                }
                #pragma unroll
                for (int nf = 0; nf < 4; ++nf) {
                    bf16x8 bfr = loadB(kb, nf);
                    #pragma unroll
                    for (int mf = 0; mf < 4; ++mf)
                        acc[nf][mf] = __builtin_amdgcn_mfma_f32_16x16x32_bf16(af[mf], bfr, acc[nf][mf], 0, 0, 0);
                }
            }
            p ^= 1;
        }

        #pragma unroll
        for (int ph = 0; ph < 2; ++ph) {
            __syncthreads();                         // fences A-buffer reuse (cs aliases A)
            if (wm == ph) {
                #pragma unroll
                for (int nf = 0; nf < 4; ++nf)
                    #pragma unroll
                    for (int mf = 0; mf < 4; ++mf)
                        #pragma unroll
                        for (int r = 0; r < 4; ++r)
                            sm.cs[mf * 16 + g * 4 + r][wn * 64 + nf * 16 + c] =
                                (unsigned short)(__float_as_uint(acc[nf][mf][r]) >> 16);
            }
            __syncthreads();
            int row = tid >> 3, ch = tid & 7;
            int grow = m0 + ph * 64 + row;
            if ((grow & 511) >= 32) {                // exact blocks own rows l<32
                unsigned short* dst = &C[(size_t)grow * CW + ni * 256 + ch * 32];
                #pragma unroll
                for (int q = 0; q < 4; ++q)
                    *(uint4*)(dst + q * 8) = *(const uint4*)&sm.cs[row][ch * 32 + q * 8];
            }
        }
    } else {
        // ============ exact path: 3-term fp32-split, rows 0..31/batch, 8 waves ============
        const int eb = blockIdx.x;
        const int bq = eb >> 3, ni = eb & 7;
        const int m0 = bq * NL;
        const unsigned* Bhi = bpack;
        const unsigned* Blo = bpack + 524288u;

        f32x4 acc[2][2];
        #pragma unroll
        for (int nf = 0; nf < 2; ++nf)
            #pragma unroll
            for (int mf = 0; mf < 2; ++mf) acc[nf][mf] = (f32x4){0.f, 0.f, 0.f, 0.f};

        const float* xr0 = x + (size_t)(m0 + c) * ND + g * 8;
        #pragma unroll 2
        for (int kb = 0; kb < 16; ++kb) {
            bf16x8 ah[2], al[2];
            #pragma unroll
            for (int mf = 0; mf < 2; ++mf) {
                const float* p = xr0 + mf * (16 * ND) + kb * 32;
                float4 a0 = *(const float4*)p;
                float4 a1 = *(const float4*)(p + 4);
                float f[8] = {a0.x, a0.y, a0.z, a0.w, a1.x, a1.y, a1.z, a1.w};
                float lo[8];
                #pragma unroll
                for (int j = 0; j < 8; ++j) {
                    float hif = __uint_as_float(__float_as_uint(f[j]) & 0xFFFF0000u);
                    lo[j] = f[j] - hif;
                }
                u32x4 uh, ul;
                uh.x = pktr(f[0], f[1]); uh.y = pktr(f[2], f[3]);
                uh.z = pktr(f[4], f[5]); uh.w = pktr(f[6], f[7]);
                ul.x = pktr(lo[0], lo[1]); ul.y = pktr(lo[2], lo[3]);
                ul.z = pktr(lo[4], lo[5]); ul.w = pktr(lo[6], lo[7]);
                ah[mf] = __builtin_bit_cast(bf16x8, uh);
                al[mf] = __builtin_bit_cast(bf16x8, ul);
            }
            #pragma unroll
            for (int nf = 0; nf < 2; ++nf) {
                int nt = ni * 16 + wave * 2 + nf;
                size_t bo = ((size_t)(nt * 16 + kb) * 64 + lane) * 4;
                bf16x8 bh = *(const bf16x8*)(Bhi + bo);
                bf16x8 bl = *(const bf16x8*)(Blo + bo);
                #pragma unroll
                for (int mf = 0; mf < 2; ++mf) {
                    acc[nf][mf] = __builtin_amdgcn_mfma_f32_16x16x32_bf16(ah[mf], bh, acc[nf][mf], 0, 0, 0);
                    acc[nf][mf] = __builtin_amdgcn_mfma_f32_16x16x32_bf16(al[mf], bh, acc[nf][mf], 0, 0, 0);
                    acc[nf][mf] = __builtin_amdgcn_mfma_f32_16x16x32_bf16(ah[mf], bl, acc[nf][mf], 0, 0, 0);
                }
            }
        }

        // hi out: rows 0..31 x 256 cols, all 8 waves
        #pragma unroll
        for (int nf = 0; nf < 2; ++nf)
            #pragma unroll
            for (int mf = 0; mf < 2; ++mf)
                #pragma unroll
                for (int r = 0; r < 4; ++r)
                    sm.cs[mf * 16 + g * 4 + r][(wave * 2 + nf) * 16 + c] =
                        (unsigned short)(__float_as_uint(acc[nf][mf][r]) >> 16);
        __syncthreads();
        #pragma unroll
        for (int i = 0; i < 2; ++i) {
            int id = tid + 512 * i;
            int row = id >> 5, cg = id & 31;
            *(uint4*)&C[(size_t)(m0 + row) * CW + ni * 256 + cg * 8] = *(const uint4*)&sm.cs[row][cg * 8];
        }
        __syncthreads();
        // lo out (rows 0..19)
        #pragma unroll
        for (int nf = 0; nf < 2; ++nf)
            #pragma unroll
            for (int mf = 0; mf < 2; ++mf)
                #pragma unroll
                for (int r = 0; r < 4; ++r) {
                    float v = acc[nf][mf][r];
                    float hif = __uint_as_float(__float_as_uint(v) & 0xFFFF0000u);
                    sm.cs[mf * 16 + g * 4 + r][(wave * 2 + nf) * 16 + c] =
                        (unsigned short)(__float_as_uint(v - hif) >> 16);
                }
        __syncthreads();
        #pragma unroll
        for (int i = 0; i < 2; ++i) {
            int id = tid + 512 * i;
            int row = id >> 5, cg = id & 31;
            if (row < 20)
                *(uint4*)&Clo[((size_t)bq * 20 + row) * CW + ni * 256 + cg * 8] = *(const uint4*)&sm.cs[row][cg * 8];
        }
    }
}

// ---------- stats_all: blocks 0..1023 = bf16 stats; 1024..1087 = exact stats ----------
__global__ __launch_bounds__(256) void stats_all(
    const unsigned short* __restrict__ C, const unsigned short* __restrict__ Clo,
    const float* __restrict__ bt, const float* __restrict__ bs,
    float* __restrict__ rowpart, float* __restrict__ exstat)
{
    __shared__ unsigned short stg[88][SPAD];
    const int tid = threadIdx.x;

    if (blockIdx.x < 1024) {
        const int bid = blockIdx.x;
        const int q = bid & 3, lc = (bid >> 2) & 7, b = bid >> 5;
        const int l0 = lc * 64;
        const int cq = tid & 31, rg = tid >> 5;
        const float inv25 = 1.f / 25.f;

        float s[8], qa[8];
        #pragma unroll
        for (int r = 0; r < 8; ++r) { s[r] = 0.f; qa[r] = 0.f; }

        for (int ch = 0; ch < 4; ++ch) {
            int cb = q * 512 + ch * 128;
            __syncthreads();
            for (int i = tid; i < 1408; i += 256) {
                int si = i >> 4, cg = i & 15;
                int gl = l0 - 12 + si;
                gl = gl < 0 ? 0 : (gl > NL - 1 ? NL - 1 : gl);
                *(uint4*)&stg[si][cg * 8] = *(const uint4*)&C[(size_t)(b * NL + gl) * CW + cb + cg * 8];
            }
            __syncthreads();

            float bv[4];
            {
                float4 b4 = q < 2 ? *(const float4*)&bt[cb + cq * 4]
                                  : *(const float4*)&bs[cb - 1024 + cq * 4];
                bv[0] = b4.x; bv[1] = b4.y; bv[2] = b4.z; bv[3] = b4.w;
            }
            float run[4] = {0.f, 0.f, 0.f, 0.f};
            #pragma unroll
            for (int w = 0; w < 25; ++w) {
                ushort4 u = *(const ushort4*)&stg[rg * 8 + w][cq * 4];
                run[0] += bf2f(u.x); run[1] += bf2f(u.y); run[2] += bf2f(u.z); run[3] += bf2f(u.w);
            }
            #pragma unroll
            for (int rr = 0; rr < 8; ++rr) {
                if (rr > 0) {
                    ushort4 un = *(const ushort4*)&stg[rg * 8 + rr + 24][cq * 4];
                    ushort4 uo = *(const ushort4*)&stg[rg * 8 + rr - 1][cq * 4];
                    run[0] += bf2f(un.x) - bf2f(uo.x); run[1] += bf2f(un.y) - bf2f(uo.y);
                    run[2] += bf2f(un.z) - bf2f(uo.z); run[3] += bf2f(un.w) - bf2f(uo.w);
                }
                float pre[4];
                if (q < 2) {
                    ushort4 uc = *(const ushort4*)&stg[rg * 8 + rr + 12][cq * 4];
                    pre[0] = bf2f(uc.x) - run[0] * inv25 + bv[0];
                    pre[1] = bf2f(uc.y) - run[1] * inv25 + bv[1];
                    pre[2] = bf2f(uc.z) - run[2] * inv25 + bv[2];
                    pre[3] = bf2f(uc.w) - run[3] * inv25 + bv[3];
                } else {
                    pre[0] = run[0] * inv25 + bv[0];
                    pre[1] = run[1] * inv25 + bv[1];
                    pre[2] = run[2] * inv25 + bv[2];
                    pre[3] = run[3] * inv25 + bv[3];
                }
                s[rr]  += pre[0] + pre[1] + pre[2] + pre[3];
                qa[rr] += pre[0] * pre[0] + pre[1] * pre[1] + pre[2] * pre[2] + pre[3] * pre[3];
            }
        }

        #pragma unroll
        for (int rr = 0; rr < 8; ++rr)
            #pragma unroll
            for (int o = 1; o < 32; o <<= 1) {
                s[rr]  += __shfl_xor(s[rr], o);
                qa[rr] += __shfl_xor(qa[rr], o);
            }
        if (cq == 0) {
            #pragma unroll
            for (int rr = 0; rr < 8; ++rr) {
                size_t gr = (size_t)b * NL + l0 + rg * 8 + rr;
                rowpart[(gr * 4 + q) * 2 + 0] = s[rr];
                rowpart[(gr * 4 + q) * 2 + 1] = qa[rr];
            }
        }
    } else {
        // exact stats: one wave per (b, chunk) instance
        const int inst = (blockIdx.x - 1024) * 4 + (tid >> 6);
        const int b = inst >> 3, chunk = inst & 7;
        const int t = tid & 63;
        const int c4 = chunk * 256 + t * 4;
        const bool isU = chunk < 4;
        const float inv25 = 1.f / 25.f;

        float bias[4];
        {
            float4 b4 = isU ? *(const float4*)&bt[c4] : *(const float4*)&bs[c4 - 1024];
            bias[0] = b4.x; bias[1] = b4.y; bias[2] = b4.z; bias[3] = b4.w;
        }
        float s[8], q[8];
        #pragma unroll
        for (int r = 0; r < 8; ++r) { s[r] = 0.f; q[r] = 0.f; }

        float cs2[4] = {0, 0, 0, 0}, v0[4], keep[8][4];
        #pragma unroll
        for (int j = 0; j < 20; ++j) {
            ushort4 h  = *(const ushort4*)&C[(size_t)(b * NL + j) * CW + c4];
            ushort4 lo = *(const ushort4*)&Clo[((size_t)b * 20 + j) * CW + c4];
            float u[4] = {bf2f(h.x) + bf2f(lo.x), bf2f(h.y) + bf2f(lo.y),
                          bf2f(h.z) + bf2f(lo.z), bf2f(h.w) + bf2f(lo.w)};
            if (j == 0) {
                #pragma unroll
                for (int k = 0; k < 4; ++k) v0[k] = u[k];
            }
            if (j < 8) {
                #pragma unroll
                for (int k = 0; k < 4; ++k) keep[j][k] = u[k];
            }
            #pragma unroll
            for (int k = 0; k < 4; ++k) cs2[k] += u[k];
            if (j >= 12) {
                const int l = j - 12;
                const float w0 = (float)(24 - j);
                #pragma unroll
                for (int k = 0; k < 4; ++k) {
                    float ma = (cs2[k] + w0 * v0[k]) * inv25;
                    float pre = isU ? (keep[l][k] - ma + bias[k]) : (ma + bias[k]);
                    s[l] += pre;
                    q[l] += pre * pre;
                }
            }
        }
        #pragma unroll
        for (int r = 0; r < 8; ++r)
            #pragma unroll
            for (int o = 1; o < 64; o <<= 1) {
                s[r] += __shfl_xor(s[r], o);
                q[r] += __shfl_xor(q[r], o);
            }
        if (t == 0) {
            #pragma unroll
            for (int r = 0; r < 8; ++r) {
                exstat[(((size_t)b * 8 + chunk) * 8 + r) * 2 + 0] = s[r];
                exstat[(((size_t)b * 8 + chunk) * 8 + r) * 2 + 1] = q[r];
            }
        }
    }
}

// ---------- exact_apply: exact med + W2 logit partials, per 128-h-col slice ----------
__global__ __launch_bounds__(64) void exact_apply(
    const unsigned short* __restrict__ C, const unsigned short* __restrict__ Clo,
    const float* __restrict__ bt, const float* __restrict__ gt, const float* __restrict__ bet,
    const float* __restrict__ bs, const float* __restrict__ gs, const float* __restrict__ bes,
    const float* __restrict__ W2, const float* __restrict__ exstat,
    float* __restrict__ exlg)
{
    const int t = threadIdx.x;
    const int chunk = blockIdx.x & 7, b = blockIdx.x >> 3;
    const int h2 = chunk * 128 + t * 2;
    const float inv25 = 1.f / 25.f;

    float mu_t[8], rs_t[8], mu_s[8], rs_s[8];
    #pragma unroll
    for (int l = 0; l < 8; ++l) {
        float st = 0.f, qt = 0.f, ss = 0.f, qs = 0.f;
        #pragma unroll
        for (int ch = 0; ch < 4; ++ch) {
            st += exstat[(((size_t)b * 8 + ch) * 8 + l) * 2 + 0];
            qt += exstat[(((size_t)b * 8 + ch) * 8 + l) * 2 + 1];
            ss += exstat[(((size_t)b * 8 + 4 + ch) * 8 + l) * 2 + 0];
            qs += exstat[(((size_t)b * 8 + 4 + ch) * 8 + l) * 2 + 1];
        }
        mu_t[l] = st * (1.f / NH);
        rs_t[l] = rsqrtf(qt * (1.f / NH) - mu_t[l] * mu_t[l] + 1e-5f);
        mu_s[l] = ss * (1.f / NH);
        rs_s[l] = rsqrtf(qs * (1.f / NH) - mu_s[l] * mu_s[l] + 1e-5f);
    }

    float btv[2], gtv[2], bev[2], bsv[2], gsv[2], besv[2], w2r[2][NE];
    #pragma unroll
    for (int k = 0; k < 2; ++k) {
        int h = h2 + k;
        btv[k] = bt[h]; gtv[k] = gt[h]; bev[k] = bet[h];
        bsv[k] = bs[h]; gsv[k] = gs[h]; besv[k] = bes[h];
        const float4* wp = (const float4*)&W2[(size_t)h * NE];
        float4 a = wp[0], c2 = wp[1];
        w2r[k][0] = a.x;  w2r[k][1] = a.y;  w2r[k][2] = a.z;  w2r[k][3] = a.w;
        w2r[k][4] = c2.x; w2r[k][5] = c2.y; w2r[k][6] = c2.z; w2r[k][7] = c2.w;
    }

    float csU[2] = {0, 0}, csV[2] = {0, 0}, v0U[2], v0V[2], keepU[8][2];
    float lg[8][NE];
    #pragma unroll
    for (int l = 0; l < 8; ++l)
        #pragma unroll
        for (int e = 0; e < NE; ++e) lg[l][e] = 0.f;

    #pragma unroll
    for (int j = 0; j < 20; ++j) {
        size_t rb = (size_t)(b * NL + j) * CW;
        size_t lb = ((size_t)b * 20 + j) * CW;
        ushort2 hu  = *(const ushort2*)&C[rb + h2];
        ushort2 lu  = *(const ushort2*)&Clo[lb + h2];
        ushort2 hv  = *(const ushort2*)&C[rb + NH + h2];
        ushort2 lv  = *(const ushort2*)&Clo[lb + NH + h2];
        float u[2] = {bf2f(hu.x) + bf2f(lu.x), bf2f(hu.y) + bf2f(lu.y)};
        float v[2] = {bf2f(hv.x) + bf2f(lv.x), bf2f(hv.y) + bf2f(lv.y)};
        if (j == 0) {
            #pragma unroll
            for (int k = 0; k < 2; ++k) { v0U[k] = u[k]; v0V[k] = v[k]; }
        }
        if (j < 8) {
            #pragma unroll
            for (int k = 0; k < 2; ++k) keepU[j][k] = u[k];
        }
        #pragma unroll
        for (int k = 0; k < 2; ++k) { csU[k] += u[k]; csV[k] += v[k]; }
        if (j >= 12) {
            const int l = j - 12;
            const float w0 = (float)(24 - j);
            #pragma unroll
            for (int k = 0; k < 2; ++k) {
                float maU = (csU[k] + w0 * v0U[k]) * inv25;
                float maV = (csV[k] + w0 * v0V[k]) * inv25;
                float tn = ((keepU[l][k] - maU + btv[k]) - mu_t[l]) * rs_t[l] * gtv[k] + bev[k];
                float sn = ((maV + bsv[k]) - mu_s[l]) * rs_s[l] * gsv[k] + besv[k];
                float m = tn + sn; m = m > 0.f ? m : 0.f;
                #pragma unroll
                for (int e = 0; e < NE; ++e) lg[l][e] = fmaf(m, w2r[k][e], lg[l][e]);
            }
        }
    }
    #pragma unroll
    for (int l = 0; l < 8; ++l)
        #pragma unroll
        for (int e = 0; e < NE; ++e)
            #pragma unroll
            for (int o = 1; o < 64; o <<= 1)
                lg[l][e] += __shfl_xor(lg[l][e], o);
    if (t == 0) {
        #pragma unroll
        for (int l = 0; l < 8; ++l)
            #pragma unroll
            for (int e = 0; e < NE; ++e)
                exlg[(((size_t)b * 8 + chunk) * 8 + l) * NE + e] = lg[l][e];
    }
}

// ---------- apply_k: MA+LN+med+W2 logit partials per col-quarter ----------
__global__ __launch_bounds__(256) void apply_k(
    const unsigned short* __restrict__ C,
    const float* __restrict__ bt, const float* __restrict__ gt, const float* __restrict__ bet,
    const float* __restrict__ bs, const float* __restrict__ gs, const float* __restrict__ bes,
    const float* __restrict__ W2, const float* __restrict__ rowpart,
    float* __restrict__ lgpart)
{
    __shared__ unsigned short stgU[88][SPAD];
    __shared__ unsigned short stgV[88][SPAD];
    __shared__ float4 rowstat[64];

    const int tid = threadIdx.x;
    const int bid = blockIdx.x;
    const int q = bid & 3, lc = (bid >> 2) & 7, b = bid >> 5;
    const int l0 = lc * 64;
    const int cq = tid & 31, rg = tid >> 5;
    const float inv25 = 1.f / 25.f;

    if (tid < 64) {
        size_t gr = (size_t)b * NL + l0 + tid;
        const float* p = &rowpart[gr * 8];
        float st = p[0] + p[2], qt = p[1] + p[3];
        float ss = p[4] + p[6], qs = p[5] + p[7];
        float mut = st * (1.f / NH), mus = ss * (1.f / NH);
        float vt = qt * (1.f / NH) - mut * mut;
        float vs = qs * (1.f / NH) - mus * mus;
        rowstat[tid] = make_float4(mut, rsqrtf(vt + 1e-5f), mus, rsqrtf(vs + 1e-5f));
    }

    float lgp[8][NE];
    #pragma unroll
    for (int r = 0; r < 8; ++r)
        #pragma unroll
        for (int e = 0; e < NE; ++e) lgp[r][e] = 0.f;

    for (int ch = 0; ch < 2; ++ch) {
        int hb = q * 256 + ch * 128;
        __syncthreads();
        for (int i = tid; i < 1408; i += 256) {
            int si = i >> 4, cg = i & 15;
            int gl = l0 - 12 + si;
            gl = gl < 0 ? 0 : (gl > NL - 1 ? NL - 1 : gl);
            size_t rb = (size_t)(b * NL + gl) * CW;
            *(uint4*)&stgU[si][cg * 8] = *(const uint4*)&C[rb + hb + cg * 8];
            *(uint4*)&stgV[si][cg * 8] = *(const uint4*)&C[rb + NH + hb + cg * 8];
        }
        __syncthreads();

        int col = hb + cq * 4;
        float4 btv = *(const float4*)&bt[col],  gtv = *(const float4*)&gt[col];
        float4 bev = *(const float4*)&bet[col], bsv = *(const float4*)&bs[col];
        float4 gsv = *(const float4*)&gs[col],  besv = *(const float4*)&bes[col];
        float btr[4] = {btv.x, btv.y, btv.z, btv.w};
        float gtr[4] = {gtv.x, gtv.y, gtv.z, gtv.w};
        float ber[4] = {bev.x, bev.y, bev.z, bev.w};
        float bsr[4] = {bsv.x, bsv.y, bsv.z, bsv.w};
        float gsr[4] = {gsv.x, gsv.y, gsv.z, gsv.w};
        float besr[4] = {besv.x, besv.y, besv.z, besv.w};
        float w2r[4][NE];
        #pragma unroll
        for (int j = 0; j < 4; ++j) {
            const float4* wp = (const float4*)&W2[(size_t)(col + j) * NE];
            float4 a = wp[0], c2 = wp[1];
            w2r[j][0] = a.x;  w2r[j][1] = a.y;  w2r[j][2] = a.z;  w2r[j][3] = a.w;
            w2r[j][4] = c2.x; w2r[j][5] = c2.y; w2r[j][6] = c2.z; w2r[j][7] = c2.w;
        }

        float runU[4] = {0.f, 0.f, 0.f, 0.f}, runV[4] = {0.f, 0.f, 0.f, 0.f};
        #pragma unroll
        for (int w = 0; w < 25; ++w) {
            ushort4 u = *(const ushort4*)&stgU[rg * 8 + w][cq * 4];
            ushort4 v = *(const ushort4*)&stgV[rg * 8 + w][cq * 4];
            runU[0] += bf2f(u.x); runU[1] += bf2f(u.y); runU[2] += bf2f(u.z); runU[3] += bf2f(u.w);
            runV[0] += bf2f(v.x); runV[1] += bf2f(v.y); runV[2] += bf2f(v.z); runV[3] += bf2f(v.w);
        }
        #pragma unroll
        for (int rr = 0; rr < 8; ++rr) {
            if (rr > 0) {
                ushort4 un = *(const ushort4*)&stgU[rg * 8 + rr + 24][cq * 4];
                ushort4 uo = *(const ushort4*)&stgU[rg * 8 + rr - 1][cq * 4];
                ushort4 vn = *(const ushort4*)&stgV[rg * 8 + rr + 24][cq * 4];
                ushort4 vo = *(const ushort4*)&stgV[rg * 8 + rr - 1][cq * 4];
                runU[0] += bf2f(un.x) - bf2f(uo.x); runU[1] += bf2f(un.y) - bf2f(uo.y);
                runU[2] += bf2f(un.z) - bf2f(uo.z); runU[3] += bf2f(un.w) - bf2f(uo.w);
                runV[0] += bf2f(vn.x) - bf2f(vo.x); runV[1] += bf2f(vn.y) - bf2f(vo.y);
                runV[2] += bf2f(vn.z) - bf2f(vo.z); runV[3] += bf2f(vn.w) - bf2f(vo.w);
            }
            float4 rs = rowstat[rg * 8 + rr];
            ushort4 uc = *(const ushort4*)&stgU[rg * 8 + rr + 12][cq * 4];
            float cen[4] = {bf2f(uc.x), bf2f(uc.y), bf2f(uc.z), bf2f(uc.w)};
            float med[4];
            #pragma unroll
            for (int j = 0; j < 4; ++j) {
                float tn = ((cen[j] - runU[j] * inv25 + btr[j]) - rs.x) * rs.y * gtr[j] + ber[j];
                float sn = ((runV[j] * inv25 + bsr[j]) - rs.z) * rs.w * gsr[j] + besr[j];
                float m = tn + sn;
                med[j] = m > 0.f ? m : 0.f;
            }
            #pragma unroll
            for (int e = 0; e < NE; ++e)
                lgp[rr][e] = fmaf(med[0], w2r[0][e], fmaf(med[1], w2r[1][e],
                             fmaf(med[2], w2r[2][e], fmaf(med[3], w2r[3][e], lgp[rr][e]))));
        }
    }

    #pragma unroll
    for (int rr = 0; rr < 8; ++rr)
        #pragma unroll
        for (int e = 0; e < NE; ++e)
            #pragma unroll
            for (int o = 1; o < 32; o <<= 1)
                lgp[rr][e] += __shfl_xor(lgp[rr][e], o);
    if (cq == 0) {
        #pragma unroll
        for (int rr = 0; rr < 8; ++rr) {
            size_t gr = (size_t)b * NL + l0 + rg * 8 + rr;
            #pragma unroll
            for (int e = 0; e < NE; ++e)
                lgpart[(gr * 4 + q) * NE + e] = lgp[rr][e];
        }
    }
}

// ---------- final_all: blocks 0..63 = mask top2; block 64 = exact gates ----------
__global__ __launch_bounds__(256) void final_all(
    const float* __restrict__ lgpart, const float* __restrict__ exlg,
    const float* __restrict__ b2,
    unsigned* __restrict__ mb, float* __restrict__ gates)
{
    const int t = threadIdx.x;
    if (blockIdx.x < 64) {
        int row = blockIdx.x * 256 + t;
        int b = row >> 9, l = row & (NL - 1);
        float lg[NE];
        #pragma unroll
        for (int e = 0; e < NE; ++e) lg[e] = b2[e];
        #pragma unroll
        for (int qq = 0; qq < 4; ++qq)
            #pragma unroll
            for (int e = 0; e < NE; ++e)
                lg[e] += lgpart[((size_t)row * 4 + qq) * NE + e];
        int i0 = 0;
        #pragma unroll
        for (int e = 1; e < NE; ++e) if (lg[e] > lg[i0]) i0 = e;
        int i1 = i0 == 0 ? 1 : 0;
        #pragma unroll
        for (int e = 0; e < NE; ++e) if (e != i0 && lg[e] > lg[i1]) i1 = e;
        unsigned m = (l < 8) ? 0u : ((1u << i0) | (1u << (8 + i1)));
        #pragma unroll
        for (int o = 1; o < 64; o <<= 1) m |= __shfl_xor(m, o);
        if ((t & 63) == 0) {
            atomicOr(&mb[2 * b + 0], m & 0xffu);
            atomicOr(&mb[2 * b + 1], m >> 8);
        }
    } else {
        const int b = t >> 3, l = t & 7;
        float lg[NE];
        #pragma unroll
        for (int e = 0; e < NE; ++e) lg[e] = b2[e];
        #pragma unroll
        for (int ch = 0; ch < 8; ++ch)
            #pragma unroll
            for (int e = 0; e < NE; ++e)
                lg[e] += exlg[(((size_t)b * 8 + ch) * 8 + l) * NE + e];
        float mx = lg[0];
        #pragma unroll
        for (int e = 1; e < NE; ++e) mx = lg[e] > mx ? lg[e] : mx;
        float p[NE]; float sum = 0.f;
        #pragma unroll
        for (int e = 0; e < NE; ++e) { p[e] = expf(lg[e] - mx); sum += p[e]; }
        float inv = 1.f / sum;
        #pragma unroll
        for (int e = 0; e < NE; ++e)
            gates[((size_t)b * 8 + l) * NE + e] = p[e] * inv;
        int i0 = 0;
        #pragma unroll
        for (int e = 1; e < NE; ++e) if (lg[e] > lg[i0]) i0 = e;
        int i1 = i0 == 0 ? 1 : 0;
        #pragma unroll
        for (int e = 0; e < NE; ++e) if (e != i0 && lg[e] > lg[i1]) i1 = e;
        unsigned m = (1u << i0) | (1u << (8 + i1));
        m |= __shfl_xor(m, 1); m |= __shfl_xor(m, 2); m |= __shfl_xor(m, 4);
        if (l == 0) {
            atomicOr(&mb[2 * b + 0], m & 0xffu);
            atomicOr(&mb[2 * b + 1], m >> 8);
        }
    }
}

// masked = gates * maskbit; denom = sum_b + 1e-4; out = masked/denom*64
__global__ void finalize_k(const unsigned* __restrict__ mb,
                           const float* __restrict__ gates,
                           float* __restrict__ out)
{
    int t = threadIdx.x;
    if (t >= 16) return;
    int l = t >> 1, e = t & 1;
    float m[NB];
    float sum = 0.f;
    #pragma unroll
    for (int bb = 0; bb < NB; ++bb) {
        float gvv = gates[((size_t)bb * 8 + l) * NE + e];
        float on  = ((mb[2 * bb + e] >> l) & 1u) ? 1.f : 0.f;
        m[bb] = gvv * on;
        sum += m[bb];
    }
    float scale = 64.f / (sum + 1e-4f);
    #pragma unroll
    for (int bb = 0; bb < NB; ++bb)
        out[(size_t)bb * (NL * NE) + l * NE + e] = m[bb] * scale;
}

extern "C" void kernel_launch(void* const* d_in, const int* in_sizes, int n_in,
                              void* d_out, int out_size, void* d_ws, size_t ws_size,
                              hipStream_t stream) {
    const float* x   = (const float*)d_in[0];
    const float* Wt  = (const float*)d_in[1];
    const float* bt  = (const float*)d_in[2];
    const float* gt  = (const float*)d_in[3];
    const float* bet = (const float*)d_in[4];
    const float* Ws  = (const float*)d_in[5];
    const float* bs  = (const float*)d_in[6];
    const float* gs  = (const float*)d_in[7];
    const float* bes = (const float*)d_in[8];
    const float* W2  = (const float*)d_in[9];
    const float* b2  = (const float*)d_in[10];
    float* out = (float*)d_out;

    char* wsb = (char*)d_ws;
    unsigned*       mbp     = (unsigned*)wsb;                          // 256 B
    float*          gates   = (float*)(wsb + 256);                     // 2 KB
    unsigned*       bpack   = (unsigned*)(wsb + 4096);                 // 4 MiB (dead after gemm_all)
    float*          rowpart = (float*)(wsb + 4096);                    // 512 KB (aliases bpack)
    float*          lgpart  = (float*)(wsb + 4096 + 524288);           // 2 MB   (aliases bpack)
    float*          exstat  = (float*)(wsb + 4096 + 524288 + 2097152); // 16 KB  (aliases bpack)
    float*          exlg    = (float*)(wsb + 4096 + 524288 + 2097152 + 16384); // 64 KB
    unsigned short* C       = (unsigned short*)(wsb + 4096 + 4194304); // 64 MiB
    unsigned short* Clo     = (unsigned short*)(wsb + 4096 + 4194304 + (size_t)NROWS * CW * 2);  // 2.5 MiB

    hipMemsetAsync(d_out, 0, sizeof(float) * NB * NL * NE, stream);
    hipMemsetAsync(mbp, 0, 256, stream);

    wprep<<<256, 256, 0, stream>>>(Wt, Ws, bpack);
    gemm_all<<<1280, 512, 0, stream>>>(x, bpack, C, Clo);
    stats_all<<<1088, 256, 0, stream>>>(C, Clo, bt, bs, rowpart, exstat);
    exact_apply<<<256, 64, 0, stream>>>(C, Clo, bt, gt, bet, bs, gs, bes, W2, exstat, exlg);
    apply_k<<<1024, 256, 0, stream>>>(C, bt, gt, bet, bs, gs, bes, W2, rowpart, lgpart);
    final_all<<<65, 256, 0, stream>>>(lgpart, exlg, b2, mbp, gates);
    finalize_k<<<1, 64, 0, stream>>>(mbp, gates, out);
}

// Round 19
// 158.553 us; speedup vs baseline: 1.6492x; 1.1585x over previous
//
#include <hip/hip_runtime.h>

#define NB 32
#define NL 512
#define ND 512
#define NH 1024
#define NE 8
#define NROWS (NB * NL)       // 16384
#define CW 2048               // C width = [U|V]
#define SPAD 136              // LDS row pad for stage buffers (16B-aligned)

typedef __attribute__((ext_vector_type(8))) short bf16x8;
typedef __attribute__((ext_vector_type(4))) float f32x4;
typedef __attribute__((ext_vector_type(4))) unsigned u32x4;

__device__ __forceinline__ unsigned short f2bf(float f) {
    unsigned u = __float_as_uint(f);
    return (unsigned short)((u + 0x7fffu + ((u >> 16) & 1u)) >> 16);
}
__device__ __forceinline__ float bf2f(unsigned short b) {
    return __uint_as_float(((unsigned)b) << 16);
}
// truncating bf16 pack of two floats: one v_perm_b32
__device__ __forceinline__ unsigned pktr(float a, float b) {
    return __builtin_amdgcn_perm(__float_as_uint(b), __float_as_uint(a), 0x07060302u);
}

// ---------- W prep: transpose + RNE split, packed [ntg][kb][lane][jp] ----------
__global__ __launch_bounds__(256) void wprep(
    const float* __restrict__ Wt, const float* __restrict__ Ws,
    unsigned* __restrict__ bpack)
{
    __shared__ float tile[64][65];
    int bid = blockIdx.x;
    int mat = bid >> 7, rem = bid & 127;
    int kt0 = (rem >> 4) << 6;
    int nt0 = (rem & 15) << 6;
    const float* W = mat ? Ws : Wt;
    unsigned* Oh = bpack;
    unsigned* Ol = bpack + 524288u;
    int t = threadIdx.x;
    #pragma unroll
    for (int i = 0; i < 16; ++i) {
        int idx = t + 256 * i;
        int k = idx >> 6, n = idx & 63;
        tile[k][n] = W[(size_t)(kt0 + k) * NH + nt0 + n];
    }
    __syncthreads();
    #pragma unroll
    for (int i = 0; i < 8; ++i) {
        int idx = t + 256 * i;
        int jp = idx & 3, lane = (idx >> 2) & 63, kbr = (idx >> 8) & 1, ntr = (idx >> 9) & 3;
        int ncol = ntr * 16 + (lane & 15);
        int kcol = kbr * 32 + ((lane >> 4) << 3) + jp * 2;
        float w0 = tile[kcol][ncol], w1 = tile[kcol + 1][ncol];
        unsigned short h0 = f2bf(w0), h1 = f2bf(w1);
        unsigned short l0 = f2bf(w0 - bf2f(h0)), l1 = f2bf(w1 - bf2f(h1));
        int ntg = mat * 64 + (nt0 >> 4) + ntr;
        int kb = (kt0 >> 5) + kbr;
        unsigned offs = ((unsigned)(ntg * 16 + kb) * 64u + (unsigned)lane) * 4u + jp;
        Oh[offs] = (unsigned)h0 | ((unsigned)h1 << 16);
        Ol[offs] = (unsigned)l0 | ((unsigned)l1 << 16);
    }
}

// ---------- gemm_all: 256-thr blocks; 0..255 = exact; 256..2303 = main 64x256 tiles ----------
__global__ __launch_bounds__(256, 4) void gemm_all(
    const float* __restrict__ x, const unsigned* __restrict__ bpack,
    unsigned short* __restrict__ C, unsigned short* __restrict__ Clo)
{
    __shared__ union {
        unsigned short A[2][64][40];     // 10 KB dbuf: 80B row stride (16B-aligned, ~2-way)
        unsigned short cs[64][264];      // 33 KB epilogue staging
    } sm;

    const int tid = threadIdx.x, lane = tid & 63, wave = tid >> 6;
    const int g = lane >> 4, c = lane & 15;

    if (blockIdx.x >= 256) {
        // ============ main path: 64x256 tile, 4 waves, 1 barrier/kb ============
        const int bid = blockIdx.x - 256;
        const int xcd = bid & 7, idx = bid >> 3;
        const int mi = xcd * 32 + (idx >> 3), ni = idx & 7;
        const int m0 = mi * 64;

        f32x4 acc[4][4];
        #pragma unroll
        for (int nf = 0; nf < 4; ++nf)
            #pragma unroll
            for (int mf = 0; mf < 4; ++mf) acc[nf][mf] = (f32x4){0.f, 0.f, 0.f, 0.f};

        const int srow = tid >> 2, sj = tid & 3;
        const float* xs = x + (size_t)(m0 + srow) * ND + sj * 8;

        auto loadB = [&](int kb2, int nf) -> bf16x8 {
            int nt = ni * 16 + wave * 4 + nf;
            return *(const bf16x8*)(bpack + ((size_t)(nt * 16 + kb2) * 64 + lane) * 4);
        };

        float4 xa = *(const float4*)xs;
        float4 xb = *(const float4*)(xs + 4);
        bf16x8 bc0 = loadB(0, 0), bc1 = loadB(0, 1), bc2 = loadB(0, 2), bc3 = loadB(0, 3);

        for (int kb = 0; kb < 16; ++kb) {
            const int p = kb & 1;
            u32x4 u;
            u.x = pktr(xa.x, xa.y); u.y = pktr(xa.z, xa.w);
            u.z = pktr(xb.x, xb.y); u.w = pktr(xb.z, xb.w);
            *(u32x4*)&sm.A[p][srow][sj * 8] = u;
            bf16x8 bn0, bn1, bn2, bn3;
            if (kb < 15) {
                const float* pn = xs + (kb + 1) * 32;
                xa = *(const float4*)pn;
                xb = *(const float4*)(pn + 4);
                bn0 = loadB(kb + 1, 0); bn1 = loadB(kb + 1, 1);
                bn2 = loadB(kb + 1, 2); bn3 = loadB(kb + 1, 3);
            }
            __syncthreads();

            bf16x8 af[4];
            #pragma unroll
            for (int mf = 0; mf < 4; ++mf)
                af[mf] = *(const bf16x8*)&sm.A[p][mf * 16 + c][g * 8];
            #pragma unroll
            for (int mf = 0; mf < 4; ++mf) {
                acc[0][mf] = __builtin_amdgcn_mfma_f32_16x16x32_bf16(af[mf], bc0, acc[0][mf], 0, 0, 0);
                acc[1][mf] = __builtin_amdgcn_mfma_f32_16x16x32_bf16(af[mf], bc1, acc[1][mf], 0, 0, 0);
                acc[2][mf] = __builtin_amdgcn_mfma_f32_16x16x32_bf16(af[mf], bc2, acc[2][mf], 0, 0, 0);
                acc[3][mf] = __builtin_amdgcn_mfma_f32_16x16x32_bf16(af[mf], bc3, acc[3][mf], 0, 0, 0);
            }
            if (kb < 15) { bc0 = bn0; bc1 = bn1; bc2 = bn2; bc3 = bn3; }
        }

        // ---- epilogue: all 4 waves write cs, then coalesced store ----
        __syncthreads();                             // fences A-buffer reuse (cs aliases A)
        #pragma unroll
        for (int nf = 0; nf < 4; ++nf)
            #pragma unroll
            for (int mf = 0; mf < 4; ++mf)
                #pragma unroll
                for (int r = 0; r < 4; ++r)
                    sm.cs[mf * 16 + g * 4 + r][wave * 64 + nf * 16 + c] =
                        (unsigned short)(__float_as_uint(acc[nf][mf][r]) >> 16);
        __syncthreads();
        #pragma unroll
        for (int i = 0; i < 8; ++i) {
            int idx2 = tid + 256 * i;
            int row = idx2 >> 5, cg = idx2 & 31;
            int grow = m0 + row;
            if ((grow & 511) >= 32)                  // exact blocks own rows l<32
                *(uint4*)&C[(size_t)grow * CW + ni * 256 + cg * 8] = *(const uint4*)&sm.cs[row][cg * 8];
        }
    } else {
        // ============ exact path: 3-term fp32-split, rows 0..31/batch, 4 waves ============
        const int eb = blockIdx.x;
        const int bq = eb >> 3, ni = eb & 7;
        const int m0 = bq * NL;
        const unsigned* Bhi = bpack;
        const unsigned* Blo = bpack + 524288u;

        f32x4 acc[4][2];
        #pragma unroll
        for (int nf = 0; nf < 4; ++nf)
            #pragma unroll
            for (int mf = 0; mf < 2; ++mf) acc[nf][mf] = (f32x4){0.f, 0.f, 0.f, 0.f};

        const float* xr0 = x + (size_t)(m0 + c) * ND + g * 8;
        #pragma unroll 2
        for (int kb = 0; kb < 16; ++kb) {
            bf16x8 ah[2], al[2];
            #pragma unroll
            for (int mf = 0; mf < 2; ++mf) {
                const float* p = xr0 + mf * (16 * ND) + kb * 32;
                float4 a0 = *(const float4*)p;
                float4 a1 = *(const float4*)(p + 4);
                float f[8] = {a0.x, a0.y, a0.z, a0.w, a1.x, a1.y, a1.z, a1.w};
                float lo[8];
                #pragma unroll
                for (int j = 0; j < 8; ++j) {
                    float hif = __uint_as_float(__float_as_uint(f[j]) & 0xFFFF0000u);
                    lo[j] = f[j] - hif;
                }
                u32x4 uh, ul;
                uh.x = pktr(f[0], f[1]); uh.y = pktr(f[2], f[3]);
                uh.z = pktr(f[4], f[5]); uh.w = pktr(f[6], f[7]);
                ul.x = pktr(lo[0], lo[1]); ul.y = pktr(lo[2], lo[3]);
                ul.z = pktr(lo[4], lo[5]); ul.w = pktr(lo[6], lo[7]);
                ah[mf] = __builtin_bit_cast(bf16x8, uh);
                al[mf] = __builtin_bit_cast(bf16x8, ul);
            }
            #pragma unroll
            for (int nf = 0; nf < 4; ++nf) {
                int nt = ni * 16 + wave * 4 + nf;
                size_t bo = ((size_t)(nt * 16 + kb) * 64 + lane) * 4;
                bf16x8 bh = *(const bf16x8*)(Bhi + bo);
                bf16x8 bl = *(const bf16x8*)(Blo + bo);
                #pragma unroll
                for (int mf = 0; mf < 2; ++mf) {
                    acc[nf][mf] = __builtin_amdgcn_mfma_f32_16x16x32_bf16(ah[mf], bh, acc[nf][mf], 0, 0, 0);
                    acc[nf][mf] = __builtin_amdgcn_mfma_f32_16x16x32_bf16(al[mf], bh, acc[nf][mf], 0, 0, 0);
                    acc[nf][mf] = __builtin_amdgcn_mfma_f32_16x16x32_bf16(ah[mf], bl, acc[nf][mf], 0, 0, 0);
                }
            }
        }

        // hi out: rows 0..31 x 256 cols
        #pragma unroll
        for (int nf = 0; nf < 4; ++nf)
            #pragma unroll
            for (int mf = 0; mf < 2; ++mf)
                #pragma unroll
                for (int r = 0; r < 4; ++r)
                    sm.cs[mf * 16 + g * 4 + r][wave * 64 + nf * 16 + c] =
                        (unsigned short)(__float_as_uint(acc[nf][mf][r]) >> 16);
        __syncthreads();
        #pragma unroll
        for (int i = 0; i < 4; ++i) {
            int idx2 = tid + 256 * i;
            int row = idx2 >> 5, cg = idx2 & 31;
            *(uint4*)&C[(size_t)(m0 + row) * CW + ni * 256 + cg * 8] = *(const uint4*)&sm.cs[row][cg * 8];
        }
        __syncthreads();
        // lo out (rows 0..19)
        #pragma unroll
        for (int nf = 0; nf < 4; ++nf)
            #pragma unroll
            for (int mf = 0; mf < 2; ++mf)
                #pragma unroll
                for (int r = 0; r < 4; ++r) {
                    float v = acc[nf][mf][r];
                    float hif = __uint_as_float(__float_as_uint(v) & 0xFFFF0000u);
                    sm.cs[mf * 16 + g * 4 + r][wave * 64 + nf * 16 + c] =
                        (unsigned short)(__float_as_uint(v - hif) >> 16);
                }
        __syncthreads();
        #pragma unroll
        for (int i = 0; i < 3; ++i) {
            int idx2 = tid + 256 * i;
            int row = idx2 >> 5, cg = idx2 & 31;
            if (row < 20)
                *(uint4*)&Clo[((size_t)bq * 20 + row) * CW + ni * 256 + cg * 8] = *(const uint4*)&sm.cs[row][cg * 8];
        }
    }
}

// ---------- stats_all: blocks 0..1023 = bf16 stats; 1024..1087 = exact stats ----------
__global__ __launch_bounds__(256) void stats_all(
    const unsigned short* __restrict__ C, const unsigned short* __restrict__ Clo,
    const float* __restrict__ bt, const float* __restrict__ bs,
    float* __restrict__ rowpart, float* __restrict__ exstat)
{
    __shared__ unsigned short stg[88][SPAD];
    const int tid = threadIdx.x;

    if (blockIdx.x < 1024) {
        const int bid = blockIdx.x;
        const int q = bid & 3, lc = (bid >> 2) & 7, b = bid >> 5;
        const int l0 = lc * 64;
        const int cq = tid & 31, rg = tid >> 5;
        const float inv25 = 1.f / 25.f;

        float s[8], qa[8];
        #pragma unroll
        for (int r = 0; r < 8; ++r) { s[r] = 0.f; qa[r] = 0.f; }

        for (int ch = 0; ch < 4; ++ch) {
            int cb = q * 512 + ch * 128;
            __syncthreads();
            for (int i = tid; i < 1408; i += 256) {
                int si = i >> 4, cg = i & 15;
                int gl = l0 - 12 + si;
                gl = gl < 0 ? 0 : (gl > NL - 1 ? NL - 1 : gl);
                *(uint4*)&stg[si][cg * 8] = *(const uint4*)&C[(size_t)(b * NL + gl) * CW + cb + cg * 8];
            }
            __syncthreads();

            float bv[4];
            {
                float4 b4 = q < 2 ? *(const float4*)&bt[cb + cq * 4]
                                  : *(const float4*)&bs[cb - 1024 + cq * 4];
                bv[0] = b4.x; bv[1] = b4.y; bv[2] = b4.z; bv[3] = b4.w;
            }
            float run[4] = {0.f, 0.f, 0.f, 0.f};
            #pragma unroll
            for (int w = 0; w < 25; ++w) {
                ushort4 u = *(const ushort4*)&stg[rg * 8 + w][cq * 4];
                run[0] += bf2f(u.x); run[1] += bf2f(u.y); run[2] += bf2f(u.z); run[3] += bf2f(u.w);
            }
            #pragma unroll
            for (int rr = 0; rr < 8; ++rr) {
                if (rr > 0) {
                    ushort4 un = *(const ushort4*)&stg[rg * 8 + rr + 24][cq * 4];
                    ushort4 uo = *(const ushort4*)&stg[rg * 8 + rr - 1][cq * 4];
                    run[0] += bf2f(un.x) - bf2f(uo.x); run[1] += bf2f(un.y) - bf2f(uo.y);
                    run[2] += bf2f(un.z) - bf2f(uo.z); run[3] += bf2f(un.w) - bf2f(uo.w);
                }
                float pre[4];
                if (q < 2) {
                    ushort4 uc = *(const ushort4*)&stg[rg * 8 + rr + 12][cq * 4];
                    pre[0] = bf2f(uc.x) - run[0] * inv25 + bv[0];
                    pre[1] = bf2f(uc.y) - run[1] * inv25 + bv[1];
                    pre[2] = bf2f(uc.z) - run[2] * inv25 + bv[2];
                    pre[3] = bf2f(uc.w) - run[3] * inv25 + bv[3];
                } else {
                    pre[0] = run[0] * inv25 + bv[0];
                    pre[1] = run[1] * inv25 + bv[1];
                    pre[2] = run[2] * inv25 + bv[2];
                    pre[3] = run[3] * inv25 + bv[3];
                }
                s[rr]  += pre[0] + pre[1] + pre[2] + pre[3];
                qa[rr] += pre[0] * pre[0] + pre[1] * pre[1] + pre[2] * pre[2] + pre[3] * pre[3];
            }
        }

        #pragma unroll
        for (int rr = 0; rr < 8; ++rr)
            #pragma unroll
            for (int o = 1; o < 32; o <<= 1) {
                s[rr]  += __shfl_xor(s[rr], o);
                qa[rr] += __shfl_xor(qa[rr], o);
            }
        if (cq == 0) {
            #pragma unroll
            for (int rr = 0; rr < 8; ++rr) {
                size_t gr = (size_t)b * NL + l0 + rg * 8 + rr;
                rowpart[(gr * 4 + q) * 2 + 0] = s[rr];
                rowpart[(gr * 4 + q) * 2 + 1] = qa[rr];
            }
        }
    } else {
        // exact stats: one wave per (b, chunk) instance
        const int inst = (blockIdx.x - 1024) * 4 + (tid >> 6);
        const int b = inst >> 3, chunk = inst & 7;
        const int t = tid & 63;
        const int c4 = chunk * 256 + t * 4;
        const bool isU = chunk < 4;
        const float inv25 = 1.f / 25.f;

        float bias[4];
        {
            float4 b4 = isU ? *(const float4*)&bt[c4] : *(const float4*)&bs[c4 - 1024];
            bias[0] = b4.x; bias[1] = b4.y; bias[2] = b4.z; bias[3] = b4.w;
        }
        float s[8], q[8];
        #pragma unroll
        for (int r = 0; r < 8; ++r) { s[r] = 0.f; q[r] = 0.f; }

        float cs2[4] = {0, 0, 0, 0}, v0[4], keep[8][4];
        #pragma unroll
        for (int j = 0; j < 20; ++j) {
            ushort4 h  = *(const ushort4*)&C[(size_t)(b * NL + j) * CW + c4];
            ushort4 lo = *(const ushort4*)&Clo[((size_t)b * 20 + j) * CW + c4];
            float u[4] = {bf2f(h.x) + bf2f(lo.x), bf2f(h.y) + bf2f(lo.y),
                          bf2f(h.z) + bf2f(lo.z), bf2f(h.w) + bf2f(lo.w)};
            if (j == 0) {
                #pragma unroll
                for (int k = 0; k < 4; ++k) v0[k] = u[k];
            }
            if (j < 8) {
                #pragma unroll
                for (int k = 0; k < 4; ++k) keep[j][k] = u[k];
            }
            #pragma unroll
            for (int k = 0; k < 4; ++k) cs2[k] += u[k];
            if (j >= 12) {
                const int l = j - 12;
                const float w0 = (float)(24 - j);
                #pragma unroll
                for (int k = 0; k < 4; ++k) {
                    float ma = (cs2[k] + w0 * v0[k]) * inv25;
                    float pre = isU ? (keep[l][k] - ma + bias[k]) : (ma + bias[k]);
                    s[l] += pre;
                    q[l] += pre * pre;
                }
            }
        }
        #pragma unroll
        for (int r = 0; r < 8; ++r)
            #pragma unroll
            for (int o = 1; o < 64; o <<= 1) {
                s[r] += __shfl_xor(s[r], o);
                q[r] += __shfl_xor(q[r], o);
            }
        if (t == 0) {
            #pragma unroll
            for (int r = 0; r < 8; ++r) {
                exstat[(((size_t)b * 8 + chunk) * 8 + r) * 2 + 0] = s[r];
                exstat[(((size_t)b * 8 + chunk) * 8 + r) * 2 + 1] = q[r];
            }
        }
    }
}

// ---------- exact_apply: exact med + W2 logit partials, per 128-h-col slice ----------
__global__ __launch_bounds__(64) void exact_apply(
    const unsigned short* __restrict__ C, const unsigned short* __restrict__ Clo,
    const float* __restrict__ bt, const float* __restrict__ gt, const float* __restrict__ bet,
    const float* __restrict__ bs, const float* __restrict__ gs, const float* __restrict__ bes,
    const float* __restrict__ W2, const float* __restrict__ exstat,
    float* __restrict__ exlg)
{
    const int t = threadIdx.x;
    const int chunk = blockIdx.x & 7, b = blockIdx.x >> 3;
    const int h2 = chunk * 128 + t * 2;
    const float inv25 = 1.f / 25.f;

    float mu_t[8], rs_t[8], mu_s[8], rs_s[8];
    #pragma unroll
    for (int l = 0; l < 8; ++l) {
        float st = 0.f, qt = 0.f, ss = 0.f, qs = 0.f;
        #pragma unroll
        for (int ch = 0; ch < 4; ++ch) {
            st += exstat[(((size_t)b * 8 + ch) * 8 + l) * 2 + 0];
            qt += exstat[(((size_t)b * 8 + ch) * 8 + l) * 2 + 1];
            ss += exstat[(((size_t)b * 8 + 4 + ch) * 8 + l) * 2 + 0];
            qs += exstat[(((size_t)b * 8 + 4 + ch) * 8 + l) * 2 + 1];
        }
        mu_t[l] = st * (1.f / NH);
        rs_t[l] = rsqrtf(qt * (1.f / NH) - mu_t[l] * mu_t[l] + 1e-5f);
        mu_s[l] = ss * (1.f / NH);
        rs_s[l] = rsqrtf(qs * (1.f / NH) - mu_s[l] * mu_s[l] + 1e-5f);
    }

    float btv[2], gtv[2], bev[2], bsv[2], gsv[2], besv[2], w2r[2][NE];
    #pragma unroll
    for (int k = 0; k < 2; ++k) {
        int h = h2 + k;
        btv[k] = bt[h]; gtv[k] = gt[h]; bev[k] = bet[h];
        bsv[k] = bs[h]; gsv[k] = gs[h]; besv[k] = bes[h];
        const float4* wp = (const float4*)&W2[(size_t)h * NE];
        float4 a = wp[0], c2 = wp[1];
        w2r[k][0] = a.x;  w2r[k][1] = a.y;  w2r[k][2] = a.z;  w2r[k][3] = a.w;
        w2r[k][4] = c2.x; w2r[k][5] = c2.y; w2r[k][6] = c2.z; w2r[k][7] = c2.w;
    }

    float csU[2] = {0, 0}, csV[2] = {0, 0}, v0U[2], v0V[2], keepU[8][2];
    float lg[8][NE];
    #pragma unroll
    for (int l = 0; l < 8; ++l)
        #pragma unroll
        for (int e = 0; e < NE; ++e) lg[l][e] = 0.f;

    #pragma unroll
    for (int j = 0; j < 20; ++j) {
        size_t rb = (size_t)(b * NL + j) * CW;
        size_t lb = ((size_t)b * 20 + j) * CW;
        ushort2 hu  = *(const ushort2*)&C[rb + h2];
        ushort2 lu  = *(const ushort2*)&Clo[lb + h2];
        ushort2 hv  = *(const ushort2*)&C[rb + NH + h2];
        ushort2 lv  = *(const ushort2*)&Clo[lb + NH + h2];
        float u[2] = {bf2f(hu.x) + bf2f(lu.x), bf2f(hu.y) + bf2f(lu.y)};
        float v[2] = {bf2f(hv.x) + bf2f(lv.x), bf2f(hv.y) + bf2f(lv.y)};
        if (j == 0) {
            #pragma unroll
            for (int k = 0; k < 2; ++k) { v0U[k] = u[k]; v0V[k] = v[k]; }
        }
        if (j < 8) {
            #pragma unroll
            for (int k = 0; k < 2; ++k) keepU[j][k] = u[k];
        }
        #pragma unroll
        for (int k = 0; k < 2; ++k) { csU[k] += u[k]; csV[k] += v[k]; }
        if (j >= 12) {
            const int l = j - 12;
            const float w0 = (float)(24 - j);
            #pragma unroll
            for (int k = 0; k < 2; ++k) {
                float maU = (csU[k] + w0 * v0U[k]) * inv25;
                float maV = (csV[k] + w0 * v0V[k]) * inv25;
                float tn = ((keepU[l][k] - maU + btv[k]) - mu_t[l]) * rs_t[l] * gtv[k] + bev[k];
                float sn = ((maV + bsv[k]) - mu_s[l]) * rs_s[l] * gsv[k] + besv[k];
                float m = tn + sn; m = m > 0.f ? m : 0.f;
                #pragma unroll
                for (int e = 0; e < NE; ++e) lg[l][e] = fmaf(m, w2r[k][e], lg[l][e]);
            }
        }
    }
    #pragma unroll
    for (int l = 0; l < 8; ++l)
        #pragma unroll
        for (int e = 0; e < NE; ++e)
            #pragma unroll
            for (int o = 1; o < 64; o <<= 1)
                lg[l][e] += __shfl_xor(lg[l][e], o);
    if (t == 0) {
        #pragma unroll
        for (int l = 0; l < 8; ++l)
            #pragma unroll
            for (int e = 0; e < NE; ++e)
                exlg[(((size_t)b * 8 + chunk) * 8 + l) * NE + e] = lg[l][e];
    }
}

// ---------- apply_k: MA+LN+med+W2 logit partials per col-quarter ----------
__global__ __launch_bounds__(256) void apply_k(
    const unsigned short* __restrict__ C,
    const float* __restrict__ bt, const float* __restrict__ gt, const float* __restrict__ bet,
    const float* __restrict__ bs, const float* __restrict__ gs, const float* __restrict__ bes,
    const float* __restrict__ W2, const float* __restrict__ rowpart,
    float* __restrict__ lgpart)
{
    __shared__ unsigned short stgU[88][SPAD];
    __shared__ unsigned short stgV[88][SPAD];
    __shared__ float4 rowstat[64];

    const int tid = threadIdx.x;
    const int bid = blockIdx.x;
    const int q = bid & 3, lc = (bid >> 2) & 7, b = bid >> 5;
    const int l0 = lc * 64;
    const int cq = tid & 31, rg = tid >> 5;
    const float inv25 = 1.f / 25.f;

    if (tid < 64) {
        size_t gr = (size_t)b * NL + l0 + tid;
        const float* p = &rowpart[gr * 8];
        float st = p[0] + p[2], qt = p[1] + p[3];
        float ss = p[4] + p[6], qs = p[5] + p[7];
        float mut = st * (1.f / NH), mus = ss * (1.f / NH);
        float vt = qt * (1.f / NH) - mut * mut;
        float vs = qs * (1.f / NH) - mus * mus;
        rowstat[tid] = make_float4(mut, rsqrtf(vt + 1e-5f), mus, rsqrtf(vs + 1e-5f));
    }

    float lgp[8][NE];
    #pragma unroll
    for (int r = 0; r < 8; ++r)
        #pragma unroll
        for (int e = 0; e < NE; ++e) lgp[r][e] = 0.f;

    for (int ch = 0; ch < 2; ++ch) {
        int hb = q * 256 + ch * 128;
        __syncthreads();
        for (int i = tid; i < 1408; i += 256) {
            int si = i >> 4, cg = i & 15;
            int gl = l0 - 12 + si;
            gl = gl < 0 ? 0 : (gl > NL - 1 ? NL - 1 : gl);
            size_t rb = (size_t)(b * NL + gl) * CW;
            *(uint4*)&stgU[si][cg * 8] = *(const uint4*)&C[rb + hb + cg * 8];
            *(uint4*)&stgV[si][cg * 8] = *(const uint4*)&C[rb + NH + hb + cg * 8];
        }
        __syncthreads();

        int col = hb + cq * 4;
        float4 btv = *(const float4*)&bt[col],  gtv = *(const float4*)&gt[col];
        float4 bev = *(const float4*)&bet[col], bsv = *(const float4*)&bs[col];
        float4 gsv = *(const float4*)&gs[col],  besv = *(const float4*)&bes[col];
        float btr[4] = {btv.x, btv.y, btv.z, btv.w};
        float gtr[4] = {gtv.x, gtv.y, gtv.z, gtv.w};
        float ber[4] = {bev.x, bev.y, bev.z, bev.w};
        float bsr[4] = {bsv.x, bsv.y, bsv.z, bsv.w};
        float gsr[4] = {gsv.x, gsv.y, gsv.z, gsv.w};
        float besr[4] = {besv.x, besv.y, besv.z, besv.w};
        float w2r[4][NE];
        #pragma unroll
        for (int j = 0; j < 4; ++j) {
            const float4* wp = (const float4*)&W2[(size_t)(col + j) * NE];
            float4 a = wp[0], c2 = wp[1];
            w2r[j][0] = a.x;  w2r[j][1] = a.y;  w2r[j][2] = a.z;  w2r[j][3] = a.w;
            w2r[j][4] = c2.x; w2r[j][5] = c2.y; w2r[j][6] = c2.z; w2r[j][7] = c2.w;
        }

        float runU[4] = {0.f, 0.f, 0.f, 0.f}, runV[4] = {0.f, 0.f, 0.f, 0.f};
        #pragma unroll
        for (int w = 0; w < 25; ++w) {
            ushort4 u = *(const ushort4*)&stgU[rg * 8 + w][cq * 4];
            ushort4 v = *(const ushort4*)&stgV[rg * 8 + w][cq * 4];
            runU[0] += bf2f(u.x); runU[1] += bf2f(u.y); runU[2] += bf2f(u.z); runU[3] += bf2f(u.w);
            runV[0] += bf2f(v.x); runV[1] += bf2f(v.y); runV[2] += bf2f(v.z); runV[3] += bf2f(v.w);
        }
        #pragma unroll
        for (int rr = 0; rr < 8; ++rr) {
            if (rr > 0) {
                ushort4 un = *(const ushort4*)&stgU[rg * 8 + rr + 24][cq * 4];
                ushort4 uo = *(const ushort4*)&stgU[rg * 8 + rr - 1][cq * 4];
                ushort4 vn = *(const ushort4*)&stgV[rg * 8 + rr + 24][cq * 4];
                ushort4 vo = *(const ushort4*)&stgV[rg * 8 + rr - 1][cq * 4];
                runU[0] += bf2f(un.x) - bf2f(uo.x); runU[1] += bf2f(un.y) - bf2f(uo.y);
                runU[2] += bf2f(un.z) - bf2f(uo.z); runU[3] += bf2f(un.w) - bf2f(uo.w);
                runV[0] += bf2f(vn.x) - bf2f(vo.x); runV[1] += bf2f(vn.y) - bf2f(vo.y);
                runV[2] += bf2f(vn.z) - bf2f(vo.z); runV[3] += bf2f(vn.w) - bf2f(vo.w);
            }
            float4 rs = rowstat[rg * 8 + rr];
            ushort4 uc = *(const ushort4*)&stgU[rg * 8 + rr + 12][cq * 4];
            float cen[4] = {bf2f(uc.x), bf2f(uc.y), bf2f(uc.z), bf2f(uc.w)};
            float med[4];
            #pragma unroll
            for (int j = 0; j < 4; ++j) {
                float tn = ((cen[j] - runU[j] * inv25 + btr[j]) - rs.x) * rs.y * gtr[j] + ber[j];
                float sn = ((runV[j] * inv25 + bsr[j]) - rs.z) * rs.w * gsr[j] + besr[j];
                float m = tn + sn;
                med[j] = m > 0.f ? m : 0.f;
            }
            #pragma unroll
            for (int e = 0; e < NE; ++e)
                lgp[rr][e] = fmaf(med[0], w2r[0][e], fmaf(med[1], w2r[1][e],
                             fmaf(med[2], w2r[2][e], fmaf(med[3], w2r[3][e], lgp[rr][e]))));
        }
    }

    #pragma unroll
    for (int rr = 0; rr < 8; ++rr)
        #pragma unroll
        for (int e = 0; e < NE; ++e)
            #pragma unroll
            for (int o = 1; o < 32; o <<= 1)
                lgp[rr][e] += __shfl_xor(lgp[rr][e], o);
    if (cq == 0) {
        #pragma unroll
        for (int rr = 0; rr < 8; ++rr) {
            size_t gr = (size_t)b * NL + l0 + rg * 8 + rr;
            #pragma unroll
            for (int e = 0; e < NE; ++e)
                lgpart[(gr * 4 + q) * NE + e] = lgp[rr][e];
        }
    }
}

// ---------- final_all: blocks 0..63 = mask top2; block 64 = exact gates ----------
__global__ __launch_bounds__(256) void final_all(
    const float* __restrict__ lgpart, const float* __restrict__ exlg,
    const float* __restrict__ b2,
    unsigned* __restrict__ mb, float* __restrict__ gates)
{
    const int t = threadIdx.x;
    if (blockIdx.x < 64) {
        int row = blockIdx.x * 256 + t;
        int b = row >> 9, l = row & (NL - 1);
        float lg[NE];
        #pragma unroll
        for (int e = 0; e < NE; ++e) lg[e] = b2[e];
        #pragma unroll
        for (int qq = 0; qq < 4; ++qq)
            #pragma unroll
            for (int e = 0; e < NE; ++e)
                lg[e] += lgpart[((size_t)row * 4 + qq) * NE + e];
        int i0 = 0;
        #pragma unroll
        for (int e = 1; e < NE; ++e) if (lg[e] > lg[i0]) i0 = e;
        int i1 = i0 == 0 ? 1 : 0;
        #pragma unroll
        for (int e = 0; e < NE; ++e) if (e != i0 && lg[e] > lg[i1]) i1 = e;
        unsigned m = (l < 8) ? 0u : ((1u << i0) | (1u << (8 + i1)));
        #pragma unroll
        for (int o = 1; o < 64; o <<= 1) m |= __shfl_xor(m, o);
        if ((t & 63) == 0) {
            atomicOr(&mb[2 * b + 0], m & 0xffu);
            atomicOr(&mb[2 * b + 1], m >> 8);
        }
    } else {
        const int b = t >> 3, l = t & 7;
        float lg[NE];
        #pragma unroll
        for (int e = 0; e < NE; ++e) lg[e] = b2[e];
        #pragma unroll
        for (int ch = 0; ch < 8; ++ch)
            #pragma unroll
            for (int e = 0; e < NE; ++e)
                lg[e] += exlg[(((size_t)b * 8 + ch) * 8 + l) * NE + e];
        float mx = lg[0];
        #pragma unroll
        for (int e = 1; e < NE; ++e) mx = lg[e] > mx ? lg[e] : mx;
        float p[NE]; float sum = 0.f;
        #pragma unroll
        for (int e = 0; e < NE; ++e) { p[e] = expf(lg[e] - mx); sum += p[e]; }
        float inv = 1.f / sum;
        #pragma unroll
        for (int e = 0; e < NE; ++e)
            gates[((size_t)b * 8 + l) * NE + e] = p[e] * inv;
        int i0 = 0;
        #pragma unroll
        for (int e = 1; e < NE; ++e) if (lg[e] > lg[i0]) i0 = e;
        int i1 = i0 == 0 ? 1 : 0;
        #pragma unroll
        for (int e = 0; e < NE; ++e) if (e != i0 && lg[e] > lg[i1]) i1 = e;
        unsigned m = (1u << i0) | (1u << (8 + i1));
        m |= __shfl_xor(m, 1); m |= __shfl_xor(m, 2); m |= __shfl_xor(m, 4);
        if (l == 0) {
            atomicOr(&mb[2 * b + 0], m & 0xffu);
            atomicOr(&mb[2 * b + 1], m >> 8);
        }
    }
}

// masked = gates * maskbit; denom = sum_b + 1e-4; out = masked/denom*64
__global__ void finalize_k(const unsigned* __restrict__ mb,
                           const float* __restrict__ gates,
                           float* __restrict__ out)
{
    int t = threadIdx.x;
    if (t >= 16) return;
    int l = t >> 1, e = t & 1;
    float m[NB];
    float sum = 0.f;
    #pragma unroll
    for (int bb = 0; bb < NB; ++bb) {
        float gvv = gates[((size_t)bb * 8 + l) * NE + e];
        float on  = ((mb[2 * bb + e] >> l) & 1u) ? 1.f : 0.f;
        m[bb] = gvv * on;
        sum += m[bb];
    }
    float scale = 64.f / (sum + 1e-4f);
    #pragma unroll
    for (int bb = 0; bb < NB; ++bb)
        out[(size_t)bb * (NL * NE) + l * NE + e] = m[bb] * scale;
}

extern "C" void kernel_launch(void* const* d_in, const int* in_sizes, int n_in,
                              void* d_out, int out_size, void* d_ws, size_t ws_size,
                              hipStream_t stream) {
    const float* x   = (const float*)d_in[0];
    const float* Wt  = (const float*)d_in[1];
    const float* bt  = (const float*)d_in[2];
    const float* gt  = (const float*)d_in[3];
    const float* bet = (const float*)d_in[4];
    const float* Ws  = (const float*)d_in[5];
    const float* bs  = (const float*)d_in[6];
    const float* gs  = (const float*)d_in[7];
    const float* bes = (const float*)d_in[8];
    const float* W2  = (const float*)d_in[9];
    const float* b2  = (const float*)d_in[10];
    float* out = (float*)d_out;

    char* wsb = (char*)d_ws;
    unsigned*       mbp     = (unsigned*)wsb;                          // 256 B
    float*          gates   = (float*)(wsb + 256);                     // 2 KB
    unsigned*       bpack   = (unsigned*)(wsb + 4096);                 // 4 MiB (dead after gemm_all)
    float*          rowpart = (float*)(wsb + 4096);                    // 512 KB (aliases bpack)
    float*          lgpart  = (float*)(wsb + 4096 + 524288);           // 2 MB   (aliases bpack)
    float*          exstat  = (float*)(wsb + 4096 + 524288 + 2097152); // 16 KB  (aliases bpack)
    float*          exlg    = (float*)(wsb + 4096 + 524288 + 2097152 + 16384); // 64 KB
    unsigned short* C       = (unsigned short*)(wsb + 4096 + 4194304); // 64 MiB
    unsigned short* Clo     = (unsigned short*)(wsb + 4096 + 4194304 + (size_t)NROWS * CW * 2);  // 2.5 MiB

    hipMemsetAsync(d_out, 0, sizeof(float) * NB * NL * NE, stream);
    hipMemsetAsync(mbp, 0, 256, stream);

    wprep<<<256, 256, 0, stream>>>(Wt, Ws, bpack);
    gemm_all<<<2304, 256, 0, stream>>>(x, bpack, C, Clo);
    stats_all<<<1088, 256, 0, stream>>>(C, Clo, bt, bs, rowpart, exstat);
    exact_apply<<<256, 64, 0, stream>>>(C, Clo, bt, gt, bet, bs, gs, bes, W2, exstat, exlg);
    apply_k<<<1024, 256, 0, stream>>>(C, bt, gt, bet, bs, gs, bes, W2, rowpart, lgpart);
    final_all<<<65, 256, 0, stream>>>(lgpart, exlg, b2, mbp, gates);
    finalize_k<<<1, 64, 0, stream>>>(mbp, gates, out);
}